// Round 11
// baseline (185.598 us; speedup 1.0000x reference)
//
#include <hip/hip_runtime.h>

#define HWSZ   16384
#define CIN    64
#define CD     128
#define COUT   64
#define BN_EPS 1e-5f

typedef __attribute__((ext_vector_type(8))) short short8x;
typedef __attribute__((ext_vector_type(4))) float floatx4;

// ws layout (float offsets):
//  25344 : a_stats[256]
//  25600 : o_stats[128]
//  32768 : big region (64 MiB): out_pre (slots 0..127) -> skipS (slots 0..63)
// d_out: a_raw -> m (bf16, in place per-plane) -> final fp32 output
#define WS_ASTAT 25344
#define WS_OSTAT 25600
#define WS_BIG   32768
#define WS_TOTAL_BYTES ((size_t)(32768 + 16777216) * 4)

__device__ __forceinline__ unsigned short f2bf(float f) {
    unsigned int u = __float_as_uint(f);
    u += 0x7fff + ((u >> 16) & 1);
    return (unsigned short)(u >> 16);
}
__device__ __forceinline__ float bf2f(unsigned short s) {
    return __uint_as_float(((unsigned int)s) << 16);
}
__device__ __forceinline__ float softplus_fast(float x) {
    return fmaxf(x, 0.f) + __logf(1.f + __expf(-fabsf(x)));
}
// works for 4 or 8 waves (sc must be float[8]); valid in thread 0
__device__ __forceinline__ float block_reduce(float v, float* sc) {
    #pragma unroll
    for (int off = 32; off >= 1; off >>= 1) v += __shfl_xor(v, off, 64);
    int wv = threadIdx.x >> 6, ln = threadIdx.x & 63;
    int nw = blockDim.x >> 6;
    if (ln == 0) sc[wv] = v;
    __syncthreads();
    float r = ((int)threadIdx.x < nw) ? sc[threadIdx.x] : 0.f;
    r += __shfl_xor(r, 1, 64);
    r += __shfl_xor(r, 2, 64);
    r += __shfl_xor(r, 4, 64);
    return r;
}

__device__ __forceinline__ short8x cvt_w8(const float* src) {
    float4 f0 = *(const float4*)(src);
    float4 f1 = *(const float4*)(src + 4);
    short8x w;
    w[0] = (short)f2bf(f0.x); w[1] = (short)f2bf(f0.y);
    w[2] = (short)f2bf(f0.z); w[3] = (short)f2bf(f0.w);
    w[4] = (short)f2bf(f1.x); w[5] = (short)f2bf(f1.y);
    w[6] = (short)f2bf(f1.z); w[7] = (short)f2bf(f1.w);
    return w;
}

// ---------------- conv_pre helpers ----------------
__device__ __forceinline__ void pre_write_lds(unsigned short* wbuf, int c, int wv,
                                              const float4 ld[4]) {
    #pragma unroll
    for (int k = 0; k < 4; ++k) {
        int px = wv * 16 + k * 4;
        wbuf[(px + 0) * 72 + c] = f2bf(ld[k].x);
        wbuf[(px + 1) * 72 + c] = f2bf(ld[k].y);
        wbuf[(px + 2) * 72 + c] = f2bf(ld[k].z);
        wbuf[(px + 3) * 72 + c] = f2bf(ld[k].w);
    }
}

__device__ __forceinline__ void pre_compute_tile(
        const unsigned short* buf, int ln, int o0, int b, int ptile,
        const short8x wfrag[4][2], const float4 biasv[4],
        unsigned short* __restrict__ out_pre, unsigned short* __restrict__ a_out) {
    floatx4 acc[4][4];
    #pragma unroll
    for (int oi = 0; oi < 4; ++oi)
        #pragma unroll
        for (int pi = 0; pi < 4; ++pi)
            acc[oi][pi] = floatx4{biasv[oi].x, biasv[oi].y, biasv[oi].z, biasv[oi].w};
    #pragma unroll
    for (int kk = 0; kk < 2; ++kk)
        #pragma unroll
        for (int pi = 0; pi < 4; ++pi) {
            short8x xfrag = *(const short8x*)((const char*)buf +
                    (pi * 16 + (ln & 15)) * 144 + (kk * 32 + (ln >> 4) * 8) * 2);
            #pragma unroll
            for (int oi = 0; oi < 4; ++oi)
                acc[oi][pi] = __builtin_amdgcn_mfma_f32_16x16x32_bf16(
                        wfrag[oi][kk], xfrag, acc[oi][pi], 0, 0, 0);
        }
    #pragma unroll
    for (int oi = 0; oi < 4; ++oi) {
        int og = o0 + oi * 16;
        unsigned short* dst = (og < 128) ? out_pre : a_out;
        int ob = (og < 128) ? og : og - 128;
        #pragma unroll
        for (int pi = 0; pi < 4; ++pi) {
            int px = ptile + pi * 16 + (ln & 15);
            #pragma unroll
            for (int r = 0; r < 4; ++r) {
                int o = ob + (ln >> 4) * 4 + r;
                dst[((size_t)b * CD + o) * HWSZ + px] = f2bf(acc[oi][pi][r]);
            }
        }
    }
}

// ---------------- K1: MFMA conv1x1 (pre + atten), depth-2 pipelined ----------------
__global__ __launch_bounds__(256) void conv_pre_mfma(
        const float* __restrict__ x, const float* __restrict__ pre_w,
        const float* __restrict__ atten_w,
        const float* __restrict__ pre_b, const float* __restrict__ atten_b,
        unsigned short* __restrict__ out_pre, unsigned short* __restrict__ a_out) {
    __shared__ unsigned short xT[2][64 * 72];   // [px][c], row 72 bf16 = 144B
    int t = threadIdx.x;
    int wv = t >> 6, ln = t & 63;
    int b = blockIdx.x >> 6;
    int poff = (blockIdx.x & 63) << 8;          // 256-px super-tile
    const float* xg = x + (size_t)b * CIN * HWSZ + poff;
    int c = ln;

    int o0 = wv * 64;
    short8x wfrag[4][2];
    #pragma unroll
    for (int oi = 0; oi < 4; ++oi)
        #pragma unroll
        for (int kk = 0; kk < 2; ++kk) {
            int row = o0 + oi * 16 + (ln & 15);
            int kcol = kk * 32 + (ln >> 4) * 8;
            const float* wsrc = (row < 128) ? (pre_w + row * 64)
                                            : (atten_w + (row - 128) * 64);
            wfrag[oi][kk] = cvt_w8(wsrc + kcol);
        }
    float4 biasv[4];
    #pragma unroll
    for (int oi = 0; oi < 4; ++oi) {
        int og = o0 + oi * 16;
        const float* bias = (og < 128) ? (pre_b + og) : (atten_b + og - 128);
        biasv[oi] = *(const float4*)(bias + (ln >> 4) * 4);
    }

    float4 lda[4], ldb[4];
    #pragma unroll
    for (int k = 0; k < 4; ++k)
        lda[k] = *(const float4*)(xg + (size_t)c * HWSZ + 0 * 64 + wv * 16 + k * 4);
    pre_write_lds(xT[0], c, wv, lda);
    #pragma unroll
    for (int k = 0; k < 4; ++k)
        lda[k] = *(const float4*)(xg + (size_t)c * HWSZ + 1 * 64 + wv * 16 + k * 4);
    __syncthreads();

    #pragma unroll
    for (int k = 0; k < 4; ++k)
        ldb[k] = *(const float4*)(xg + (size_t)c * HWSZ + 2 * 64 + wv * 16 + k * 4);
    pre_compute_tile(xT[0], ln, o0, b, poff + 0 * 64, wfrag, biasv, out_pre, a_out);
    pre_write_lds(xT[1], c, wv, lda);
    __syncthreads();

    #pragma unroll
    for (int k = 0; k < 4; ++k)
        lda[k] = *(const float4*)(xg + (size_t)c * HWSZ + 3 * 64 + wv * 16 + k * 4);
    pre_compute_tile(xT[1], ln, o0, b, poff + 1 * 64, wfrag, biasv, out_pre, a_out);
    pre_write_lds(xT[0], c, wv, ldb);
    __syncthreads();

    pre_compute_tile(xT[0], ln, o0, b, poff + 2 * 64, wfrag, biasv, out_pre, a_out);
    pre_write_lds(xT[1], c, wv, lda);
    __syncthreads();

    pre_compute_tile(xT[1], ln, o0, b, poff + 3 * 64, wfrag, biasv, out_pre, a_out);
}

// ---------------- per-channel sum/sumsq over bf16 src ----------------
__global__ __launch_bounds__(256) void chan_stats_bf16(
        const unsigned short* __restrict__ src, float* __restrict__ stats) {
    __shared__ float sc1[8], sc2[8];
    int c = blockIdx.x, b = blockIdx.y;
    const unsigned short* base = src + ((size_t)b * CD + c) * HWSZ;
    int t = threadIdx.x;
    float sum = 0.f, sq = 0.f;
    #pragma unroll
    for (int i = 0; i < 8; ++i) {
        uint4 v = *(const uint4*)(base + i * 2048 + t * 8);
        unsigned int u[4] = {v.x, v.y, v.z, v.w};
        #pragma unroll
        for (int k = 0; k < 4; ++k) {
            float lo = bf2f((unsigned short)(u[k] & 0xffff));
            float hi = bf2f((unsigned short)(u[k] >> 16));
            sum += lo + hi;
            sq  += lo * lo + hi * hi;
        }
    }
    sum = block_reduce(sum, sc1);
    __syncthreads();
    sq = block_reduce(sq, sc2);
    if (t == 0) {
        atomicAdd(&stats[c * 2 + 0], sum);
        atomicAdd(&stats[c * 2 + 1], sq);
    }
}

// ---------------- fused: BN+softplus (regs) + spat-reduce + GLOBAL-gather displace ----------------
// No image LDS: taps gathered straight from the pre plane (L2-resident, 32 KB).
// Writes m OVER the a_raw plane in d_out (own-plane, after phase-1 read) -> race-free.
struct Win9 { float v0,v1,v2,v3,v4,v5,v6,v7,v8; };
__device__ __forceinline__ Win9 extract9(uint4 qa, uint4 qb, bool s4, int sh) {
    unsigned long long A0 = ((unsigned long long)qa.y << 32) | qa.x;
    unsigned long long A1 = ((unsigned long long)qa.w << 32) | qa.z;
    unsigned long long A2 = ((unsigned long long)qb.y << 32) | qb.x;
    unsigned long long A3 = ((unsigned long long)qb.w << 32) | qb.z;
    unsigned long long B0 = s4 ? A1 : A0;
    unsigned long long B1 = s4 ? A2 : A1;
    unsigned long long B2 = s4 ? A3 : A2;
    unsigned long long r0 = sh ? ((B0 >> sh) | (B1 << (64 - sh))) : B0;
    unsigned long long r1 = sh ? ((B1 >> sh) | (B2 << (64 - sh))) : B1;
    unsigned int v8w = (unsigned int)(sh ? (B2 >> sh) : B2);
    Win9 w;
    w.v0 = bf2f((unsigned short)(r0 >>  0)); w.v1 = bf2f((unsigned short)(r0 >> 16));
    w.v2 = bf2f((unsigned short)(r0 >> 32)); w.v3 = bf2f((unsigned short)(r0 >> 48));
    w.v4 = bf2f((unsigned short)(r1 >>  0)); w.v5 = bf2f((unsigned short)(r1 >> 16));
    w.v6 = bf2f((unsigned short)(r1 >> 32)); w.v7 = bf2f((unsigned short)(r1 >> 48));
    w.v8 = bf2f((unsigned short)(v8w & 0xffff));
    return w;
}

__global__ __launch_bounds__(512) void displace_bnsp_gg(
        const unsigned short* __restrict__ pre, unsigned short* __restrict__ a_m,
        const float* __restrict__ stats, const float* __restrict__ g,
        const float* __restrict__ bb, const float* __restrict__ offsets) {
    __shared__ float sc[8];
    __shared__ float s_inv;
    int bc = blockIdx.x;
    int cc = bc & 127;
    // inline displacement params (was prep_kernel)
    float dy = offsets[(cc >> 2) * 2 + 0];
    float dx = offsets[(cc >> 2) * 2 + 1];
    float fy = floorf(dy), fx = floorf(dx);
    float wy = dy - fy, wx = dx - fx;
    int iy = (int)fy, ix = (int)fx;
    float w00 = (1.f - wy) * (1.f - wx);
    float w01 = (1.f - wy) * wx;
    float w10 = wy * (1.f - wx);
    float w11 = wy * wx;
    const float N = 262144.f;
    float mean = stats[cc * 2] / N;
    float var  = stats[cc * 2 + 1] / N - mean * mean;
    float rstd = rsqrtf(var + BN_EPS);
    float scl = rstd * g[cc];
    float shf = bb[cc] - mean * scl;
    const unsigned short* pg = pre + (size_t)bc * HWSZ;   // gather source (read-only)
    unsigned short* am = a_m + (size_t)bc * HWSZ;         // a_raw in, m out (own plane)
    int t = threadIdx.x;
    uint4 aspr[4];
    float lsum = 0.f;
    #pragma unroll
    for (int i = 0; i < 4; ++i) {
        int px = i * 4096 + t * 8;
        uint4 av = *(const uint4*)(am + px);
        unsigned int au[4] = {av.x, av.y, av.z, av.w};
        unsigned int ou[4];
        #pragma unroll
        for (int k = 0; k < 4; ++k) {
            float lo = softplus_fast(bf2f((unsigned short)(au[k] & 0xffff)) * scl + shf);
            float hi = softplus_fast(bf2f((unsigned short)(au[k] >> 16))    * scl + shf);
            lsum += lo + hi;
            ou[k] = (unsigned int)f2bf(lo) | ((unsigned int)f2bf(hi) << 16);
        }
        aspr[i] = uint4{ou[0], ou[1], ou[2], ou[3]};
    }
    lsum = block_reduce(lsum, sc);
    if (t == 0) s_inv = 1.f / lsum;
    __syncthreads();
    float inv = s_inv;
    int s = ix & 7;
    int ix8 = ix - s;
    int sh = (s & 3) * 16;
    bool s4 = s >= 4;
    #pragma unroll
    for (int i = 0; i < 4; ++i) {
        int px = i * 4096 + t * 8;
        int y = px >> 7, x0 = px & 127;
        int yy0 = y + iy, yy1 = yy0 + 1;
        float wA0 = (yy0 >= 0 && yy0 < 128) ? w00 : 0.f;
        float wA1 = (yy0 >= 0 && yy0 < 128) ? w01 : 0.f;
        float wB0 = (yy1 >= 0 && yy1 < 128) ? w10 : 0.f;
        float wB1 = (yy1 >= 0 && yy1 < 128) ? w11 : 0.f;
        int yc0 = min(max(yy0, 0), 127), yc1 = min(max(yy1, 0), 127);
        int w0 = x0 + ix8;
        uint4 z = {0u, 0u, 0u, 0u};
        uint4 qa0 = (w0 >= 0 && w0 <= 120)         ? *(const uint4*)(pg + yc0 * 128 + w0)     : z;
        uint4 qa1 = (w0 + 8 >= 0 && w0 + 8 <= 120) ? *(const uint4*)(pg + yc0 * 128 + w0 + 8) : z;
        uint4 qb0 = (w0 >= 0 && w0 <= 120)         ? *(const uint4*)(pg + yc1 * 128 + w0)     : z;
        uint4 qb1 = (w0 + 8 >= 0 && w0 + 8 <= 120) ? *(const uint4*)(pg + yc1 * 128 + w0 + 8) : z;
        Win9 va = extract9(qa0, qa1, s4, sh);
        Win9 vb = extract9(qb0, qb1, s4, sh);
        float dv0 = wA0*va.v0 + wA1*va.v1 + wB0*vb.v0 + wB1*vb.v1;
        float dv1 = wA0*va.v1 + wA1*va.v2 + wB0*vb.v1 + wB1*vb.v2;
        float dv2 = wA0*va.v2 + wA1*va.v3 + wB0*vb.v2 + wB1*vb.v3;
        float dv3 = wA0*va.v3 + wA1*va.v4 + wB0*vb.v3 + wB1*vb.v4;
        float dv4 = wA0*va.v4 + wA1*va.v5 + wB0*vb.v4 + wB1*vb.v5;
        float dv5 = wA0*va.v5 + wA1*va.v6 + wB0*vb.v5 + wB1*vb.v6;
        float dv6 = wA0*va.v6 + wA1*va.v7 + wB0*vb.v6 + wB1*vb.v7;
        float dv7 = wA0*va.v7 + wA1*va.v8 + wB0*vb.v7 + wB1*vb.v8;
        unsigned int au[4] = {aspr[i].x, aspr[i].y, aspr[i].z, aspr[i].w};
        float a0 = bf2f((unsigned short)(au[0] & 0xffff)) * inv;
        float a1 = bf2f((unsigned short)(au[0] >> 16)) * inv;
        float a2 = bf2f((unsigned short)(au[1] & 0xffff)) * inv;
        float a3 = bf2f((unsigned short)(au[1] >> 16)) * inv;
        float a4 = bf2f((unsigned short)(au[2] & 0xffff)) * inv;
        float a5 = bf2f((unsigned short)(au[2] >> 16)) * inv;
        float a6 = bf2f((unsigned short)(au[3] & 0xffff)) * inv;
        float a7 = bf2f((unsigned short)(au[3] >> 16)) * inv;
        uint4 o;
        o.x = (unsigned int)f2bf(dv0 * a0) | ((unsigned int)f2bf(dv1 * a1) << 16);
        o.y = (unsigned int)f2bf(dv2 * a2) | ((unsigned int)f2bf(dv3 * a3) << 16);
        o.z = (unsigned int)f2bf(dv4 * a4) | ((unsigned int)f2bf(dv5 * a5) << 16);
        o.w = (unsigned int)f2bf(dv6 * a6) | ((unsigned int)f2bf(dv7 * a7) << 16);
        *(uint4*)(am + px) = o;
    }
}

// ---------------- MFMA conv 128->64 + bias + skip -> skipS (big slots 0..63) ----------------
__global__ __launch_bounds__(256) void conv_post_mfma(
        const unsigned short* __restrict__ m, const float* __restrict__ post_w,
        const float* __restrict__ post_b, const float* __restrict__ x,
        unsigned short* __restrict__ skipS) {
    __shared__ unsigned short mT[128 * 128];  // byte = px*256 + ((c*2) ^ ((px&7)<<4))
    int t = threadIdx.x;
    int P0 = blockIdx.x * 128;
    int b = P0 >> 14, poff = P0 & 16383;
    int cl = t & 31, q = t >> 5;
    #pragma unroll
    for (int pass = 0; pass < 4; ++pass) {
        int c = cl + pass * 32;
        const unsigned short* mrow = m + ((size_t)b * CD + c) * HWSZ + poff;
        #pragma unroll
        for (int h = 0; h < 2; ++h) {
            int px0 = h * 64 + q * 8;
            uint4 v = *(const uint4*)(mrow + px0);
            unsigned int u[4] = {v.x, v.y, v.z, v.w};
            #pragma unroll
            for (int j = 0; j < 8; ++j) {
                unsigned short val = (unsigned short)((u[j >> 1] >> ((j & 1) * 16)) & 0xffff);
                int byteoff = (px0 + j) * 256 + ((c * 2) ^ (j << 4));
                *(unsigned short*)((char*)mT + byteoff) = val;
            }
        }
    }
    __syncthreads();
    int ln = t & 63, wv = t >> 6;
    int o0 = (wv >> 1) * 32;
    int ph = (wv & 1) * 64;
    short8x aw[2][4];
    #pragma unroll
    for (int oi = 0; oi < 2; ++oi)
        #pragma unroll
        for (int kk = 0; kk < 4; ++kk) {
            int o = o0 + oi * 16 + (ln & 15);
            aw[oi][kk] = cvt_w8(post_w + o * 128 + kk * 32 + (ln >> 4) * 8);
        }
    floatx4 acc[2][4];
    #pragma unroll
    for (int oi = 0; oi < 2; ++oi)
        #pragma unroll
        for (int pi = 0; pi < 4; ++pi) acc[oi][pi] = floatx4{0.f, 0.f, 0.f, 0.f};
    #pragma unroll
    for (int kk = 0; kk < 4; ++kk)
        #pragma unroll
        for (int pi = 0; pi < 4; ++pi) {
            int px = ph + pi * 16 + (ln & 15);
            int cb = kk * 64 + (ln >> 4) * 16;
            short8x bf = *(const short8x*)((const char*)mT + px * 256 + (cb ^ ((px & 7) << 4)));
            #pragma unroll
            for (int oi = 0; oi < 2; ++oi)
                acc[oi][pi] = __builtin_amdgcn_mfma_f32_16x16x32_bf16(aw[oi][kk], bf, acc[oi][pi], 0, 0, 0);
        }
    #pragma unroll
    for (int oi = 0; oi < 2; ++oi) {
        float4 b4 = *(const float4*)(post_b + o0 + oi * 16 + (ln >> 4) * 4);
        float bb[4] = {b4.x, b4.y, b4.z, b4.w};
        #pragma unroll
        for (int pi = 0; pi < 4; ++pi) {
            int pxg = poff + ph + pi * 16 + (ln & 15);
            #pragma unroll
            for (int r = 0; r < 4; ++r) {
                int o = o0 + oi * 16 + (ln >> 4) * 4 + r;
                float val = acc[oi][pi][r] + bb[r] + x[((size_t)b * COUT + o) * HWSZ + pxg];
                skipS[((size_t)b * CD + o) * HWSZ + pxg] = f2bf(val);
            }
        }
    }
}

// ---------------- final BN + ReLU: skipS bf16 -> d_out fp32 ----------------
__global__ __launch_bounds__(256) void bn_relu_out(
        const unsigned short* __restrict__ skipS, float* __restrict__ out,
        const float* __restrict__ stats, const float* __restrict__ g,
        const float* __restrict__ bb) {
    const float N = 262144.f;
    int t = threadIdx.x;
    #pragma unroll
    for (int k = 0; k < 4; ++k) {
        size_t gidx = (size_t)blockIdx.x * 1024 + k * 256 + t;  // 8-elem index
        size_t e = gidx * 8;
        int b = (int)(e >> 20);
        int c = (int)(e >> 14) & 63;
        int px = (int)(e & 16383);
        float mean = stats[c * 2] / N;
        float rstd = rsqrtf(stats[c * 2 + 1] / N - mean * mean + BN_EPS);
        float gc = g[c], bbc = bb[c];
        uint4 v = *(const uint4*)(skipS + ((size_t)b * CD + c) * HWSZ + px);
        unsigned int u[4] = {v.x, v.y, v.z, v.w};
        float4 o0, o1;
        float* op[8] = {&o0.x, &o0.y, &o0.z, &o0.w, &o1.x, &o1.y, &o1.z, &o1.w};
        #pragma unroll
        for (int j = 0; j < 8; ++j) {
            float val = bf2f((unsigned short)((u[j >> 1] >> ((j & 1) * 16)) & 0xffff));
            *op[j] = fmaxf((val - mean) * rstd * gc + bbc, 0.f);
        }
        *(float4*)(out + e) = o0;
        *(float4*)(out + e + 4) = o1;
    }
}

extern "C" void kernel_launch(void* const* d_in, const int* in_sizes, int n_in,
                              void* d_out, int out_size, void* d_ws, size_t ws_size,
                              hipStream_t stream) {
    const float* x          = (const float*)d_in[0];
    const float* pre_w      = (const float*)d_in[1];
    const float* pre_b      = (const float*)d_in[2];
    const float* post_w     = (const float*)d_in[3];
    const float* post_b     = (const float*)d_in[4];
    const float* atten_w    = (const float*)d_in[5];
    const float* atten_b    = (const float*)d_in[6];
    const float* atten_bn_g = (const float*)d_in[7];
    const float* atten_bn_b = (const float*)d_in[8];
    const float* offsets    = (const float*)d_in[9];
    const float* bn_g       = (const float*)d_in[10];
    const float* bn_b       = (const float*)d_in[11];
    float* out = (float*)d_out;
    float* ws  = (float*)d_ws;

    if (ws_size < WS_TOTAL_BYTES) return;

    float* a_stats = ws + WS_ASTAT;
    float* o_stats = ws + WS_OSTAT;
    unsigned short* big   = (unsigned short*)(ws + WS_BIG);  // out_pre -> skipS (slots 0..63)
    unsigned short* a_buf = (unsigned short*)d_out;          // a_raw -> m (bf16)

    hipMemsetAsync((void*)a_stats, 0, 384 * sizeof(float), stream);

    conv_pre_mfma<<<1024, 256, 0, stream>>>(x, pre_w, atten_w, pre_b, atten_b, big, a_buf);
    chan_stats_bf16<<<dim3(128, 16), 256, 0, stream>>>(a_buf, a_stats);
    displace_bnsp_gg<<<2048, 512, 0, stream>>>(big, a_buf, a_stats, atten_bn_g, atten_bn_b, offsets);
    conv_post_mfma<<<2048, 256, 0, stream>>>(a_buf, post_w, post_b, x, big);
    chan_stats_bf16<<<dim3(64, 16), 256, 0, stream>>>(big, o_stats);
    bn_relu_out<<<2048, 256, 0, stream>>>(big, out, o_stats, bn_g, bn_b);
}

// Round 12
// 164.157 us; speedup vs baseline: 1.1306x; 1.1306x over previous
//
#include <hip/hip_runtime.h>

#define HWSZ   16384
#define CIN    64
#define CD     128
#define COUT   64
#define BN_EPS 1e-5f

typedef __attribute__((ext_vector_type(8))) short short8x;
typedef __attribute__((ext_vector_type(4))) float floatx4;

// ws layout (float offsets):
//  25344 : a_stats[256]
//  25600 : o_stats[128]
//  32768 : big region (64 MiB): out_pre (slots 0..127) -> m (in place) -> skipS (slots 0..63)
// d_out: a_raw (bf16) -> dead -> final fp32 output
#define WS_ASTAT 25344
#define WS_OSTAT 25600
#define WS_BIG   32768
#define WS_TOTAL_BYTES ((size_t)(32768 + 16777216) * 4)

__device__ __forceinline__ unsigned short f2bf(float f) {
    unsigned int u = __float_as_uint(f);
    u += 0x7fff + ((u >> 16) & 1);
    return (unsigned short)(u >> 16);
}
__device__ __forceinline__ float bf2f(unsigned short s) {
    return __uint_as_float(((unsigned int)s) << 16);
}
__device__ __forceinline__ float softplus_fast(float x) {
    return fmaxf(x, 0.f) + __logf(1.f + __expf(-fabsf(x)));
}
// works for 4 or 8 waves (sc must be float[8]); valid in thread 0
__device__ __forceinline__ float block_reduce(float v, float* sc) {
    #pragma unroll
    for (int off = 32; off >= 1; off >>= 1) v += __shfl_xor(v, off, 64);
    int wv = threadIdx.x >> 6, ln = threadIdx.x & 63;
    int nw = blockDim.x >> 6;
    if (ln == 0) sc[wv] = v;
    __syncthreads();
    float r = ((int)threadIdx.x < nw) ? sc[threadIdx.x] : 0.f;
    r += __shfl_xor(r, 1, 64);
    r += __shfl_xor(r, 2, 64);
    r += __shfl_xor(r, 4, 64);
    return r;
}

__device__ __forceinline__ short8x cvt_w8(const float* src) {
    float4 f0 = *(const float4*)(src);
    float4 f1 = *(const float4*)(src + 4);
    short8x w;
    w[0] = (short)f2bf(f0.x); w[1] = (short)f2bf(f0.y);
    w[2] = (short)f2bf(f0.z); w[3] = (short)f2bf(f0.w);
    w[4] = (short)f2bf(f1.x); w[5] = (short)f2bf(f1.y);
    w[6] = (short)f2bf(f1.z); w[7] = (short)f2bf(f1.w);
    return w;
}

// ---------------- conv_pre helpers ----------------
#define OBPAD 68   // row stride (ushorts); 136B: 8B-aligned rows, bank shift 2/row

__device__ __forceinline__ void pre_write_lds(unsigned short* wbuf, int c, int wv,
                                              const float4 ld[4]) {
    #pragma unroll
    for (int k = 0; k < 4; ++k) {
        int px = wv * 16 + k * 4;
        wbuf[(px + 0) * 72 + c] = f2bf(ld[k].x);
        wbuf[(px + 1) * 72 + c] = f2bf(ld[k].y);
        wbuf[(px + 2) * 72 + c] = f2bf(ld[k].z);
        wbuf[(px + 3) * 72 + c] = f2bf(ld[k].w);
    }
}

// swapped-operand compute: D[px][o]; results staged into ob[256][OBPAD]
__device__ __forceinline__ void pre_compute_tile(
        const unsigned short* buf, unsigned short* ob, int ln, int wv,
        const short8x wfrag[4][2], const float bv[4]) {
    floatx4 acc[4][4];
    #pragma unroll
    for (int oi = 0; oi < 4; ++oi)
        #pragma unroll
        for (int pi = 0; pi < 4; ++pi)
            acc[oi][pi] = floatx4{bv[oi], bv[oi], bv[oi], bv[oi]};
    #pragma unroll
    for (int kk = 0; kk < 2; ++kk)
        #pragma unroll
        for (int pi = 0; pi < 4; ++pi) {
            short8x xfrag = *(const short8x*)((const char*)buf +
                    (pi * 16 + (ln & 15)) * 144 + (kk * 32 + (ln >> 4) * 8) * 2);
            #pragma unroll
            for (int oi = 0; oi < 4; ++oi)
                acc[oi][pi] = __builtin_amdgcn_mfma_f32_16x16x32_bf16(
                        xfrag, wfrag[oi][kk], acc[oi][pi], 0, 0, 0);
        }
    // stage to LDS: row = o (0..255), col = px (0..63)
    #pragma unroll
    for (int oi = 0; oi < 4; ++oi) {
        int row = wv * 64 + oi * 16 + (ln & 15);
        #pragma unroll
        for (int pi = 0; pi < 4; ++pi) {
            int px = pi * 16 + (ln >> 4) * 4;
            ushort4 v;
            v.x = f2bf(acc[oi][pi][0]); v.y = f2bf(acc[oi][pi][1]);
            v.z = f2bf(acc[oi][pi][2]); v.w = f2bf(acc[oi][pi][3]);
            *(ushort4*)&ob[row * OBPAD + px] = v;
        }
    }
}

// ---------------- K1: MFMA conv1x1 (pre + atten), depth-2 pipelined ----------------
// block = 256 px (4 tiles x 64 px); coalesced dwordx4 stores via LDS transpose.
__global__ __launch_bounds__(256) void conv_pre_mfma(
        const float* __restrict__ x, const float* __restrict__ pre_w,
        const float* __restrict__ atten_w,
        const float* __restrict__ pre_b, const float* __restrict__ atten_b,
        unsigned short* __restrict__ out_pre, unsigned short* __restrict__ a_out) {
    __shared__ unsigned short xT[2][64 * 72];      // input staging (2 x 9 KB)
    __shared__ unsigned short ob[256 * OBPAD];     // output staging (34 KB)
    int t = threadIdx.x;
    int wv = t >> 6, ln = t & 63;
    int b = blockIdx.x >> 6;
    int poff = (blockIdx.x & 63) << 8;             // 256-px super-tile
    const float* xg = x + (size_t)b * CIN * HWSZ + poff;
    int c = ln;

    int o0 = wv * 64;
    short8x wfrag[4][2];       // B operand: col o = ln&15, k contiguous
    #pragma unroll
    for (int oi = 0; oi < 4; ++oi)
        #pragma unroll
        for (int kk = 0; kk < 2; ++kk) {
            int row = o0 + oi * 16 + (ln & 15);
            int kcol = kk * 32 + (ln >> 4) * 8;
            const float* wsrc = (row < 128) ? (pre_w + row * 64)
                                            : (atten_w + (row - 128) * 64);
            wfrag[oi][kk] = cvt_w8(wsrc + kcol);
        }
    float bv[4];
    #pragma unroll
    for (int oi = 0; oi < 4; ++oi) {
        int og = o0 + oi * 16;
        bv[oi] = (og < 128) ? pre_b[og + (ln & 15)] : atten_b[og - 128 + (ln & 15)];
    }

    float4 lda[4], ldb[4];
    #pragma unroll
    for (int k = 0; k < 4; ++k)
        lda[k] = *(const float4*)(xg + (size_t)c * HWSZ + 0 * 64 + wv * 16 + k * 4);
    pre_write_lds(xT[0], c, wv, lda);
    #pragma unroll
    for (int k = 0; k < 4; ++k)
        lda[k] = *(const float4*)(xg + (size_t)c * HWSZ + 1 * 64 + wv * 16 + k * 4);
    __syncthreads();

    #pragma unroll
    for (int tt = 0; tt < 4; ++tt) {
        // issue loads for tile tt+2 (consumed next iteration)
        if (tt == 0) {
            #pragma unroll
            for (int k = 0; k < 4; ++k)
                ldb[k] = *(const float4*)(xg + (size_t)c * HWSZ + 2 * 64 + wv * 16 + k * 4);
        } else if (tt == 1) {
            #pragma unroll
            for (int k = 0; k < 4; ++k)
                lda[k] = *(const float4*)(xg + (size_t)c * HWSZ + 3 * 64 + wv * 16 + k * 4);
        }
        // compute tile tt -> ob; write xT for tile tt+1
        pre_compute_tile(xT[tt & 1], ob, ln, wv, wfrag, bv);
        if (tt == 0)      pre_write_lds(xT[1], c, wv, lda);
        else if (tt == 1) pre_write_lds(xT[0], c, wv, ldb);
        else if (tt == 2) pre_write_lds(xT[1], c, wv, lda);
        __syncthreads();
        // store phase: 8 rounds of dwordx4 (rows 0..127 pre, 128..255 atten)
        int ptile = poff + tt * 64;
        #pragma unroll
        for (int j = 0; j < 8; ++j) {
            int row = j * 32 + (t >> 3);
            int px  = (t & 7) * 8;
            uint4 v = *(const uint4*)&ob[row * OBPAD + px];
            unsigned short* dst = (row < 128) ? out_pre : a_out;
            int o = row & 127;
            *(uint4*)(dst + ((size_t)b * CD + o) * HWSZ + ptile + px) = v;
        }
        __syncthreads();   // ob consumed before next tile overwrites
    }
}

// ---------------- per-channel sum/sumsq over bf16 src ----------------
__global__ __launch_bounds__(256) void chan_stats_bf16(
        const unsigned short* __restrict__ src, float* __restrict__ stats) {
    __shared__ float sc1[8], sc2[8];
    int c = blockIdx.x, b = blockIdx.y;
    const unsigned short* base = src + ((size_t)b * CD + c) * HWSZ;
    int t = threadIdx.x;
    float sum = 0.f, sq = 0.f;
    #pragma unroll
    for (int i = 0; i < 8; ++i) {
        uint4 v = *(const uint4*)(base + i * 2048 + t * 8);
        unsigned int u[4] = {v.x, v.y, v.z, v.w};
        #pragma unroll
        for (int k = 0; k < 4; ++k) {
            float lo = bf2f((unsigned short)(u[k] & 0xffff));
            float hi = bf2f((unsigned short)(u[k] >> 16));
            sum += lo + hi;
            sq  += lo * lo + hi * hi;
        }
    }
    sum = block_reduce(sum, sc1);
    __syncthreads();
    sq = block_reduce(sq, sc2);
    if (t == 0) {
        atomicAdd(&stats[c * 2 + 0], sum);
        atomicAdd(&stats[c * 2 + 1], sq);
    }
}

// ---------------- fused: BN+softplus (regs) + spat-reduce + displace + mul ----------------
struct Win9 { float v0,v1,v2,v3,v4,v5,v6,v7,v8; };
__device__ __forceinline__ Win9 extract9(uint4 qa, uint4 qb, bool s4, int sh) {
    unsigned long long A0 = ((unsigned long long)qa.y << 32) | qa.x;
    unsigned long long A1 = ((unsigned long long)qa.w << 32) | qa.z;
    unsigned long long A2 = ((unsigned long long)qb.y << 32) | qb.x;
    unsigned long long A3 = ((unsigned long long)qb.w << 32) | qb.z;
    unsigned long long B0 = s4 ? A1 : A0;
    unsigned long long B1 = s4 ? A2 : A1;
    unsigned long long B2 = s4 ? A3 : A2;
    unsigned long long r0 = sh ? ((B0 >> sh) | (B1 << (64 - sh))) : B0;
    unsigned long long r1 = sh ? ((B1 >> sh) | (B2 << (64 - sh))) : B1;
    unsigned int v8w = (unsigned int)(sh ? (B2 >> sh) : B2);
    Win9 w;
    w.v0 = bf2f((unsigned short)(r0 >>  0)); w.v1 = bf2f((unsigned short)(r0 >> 16));
    w.v2 = bf2f((unsigned short)(r0 >> 32)); w.v3 = bf2f((unsigned short)(r0 >> 48));
    w.v4 = bf2f((unsigned short)(r1 >>  0)); w.v5 = bf2f((unsigned short)(r1 >> 16));
    w.v6 = bf2f((unsigned short)(r1 >> 32)); w.v7 = bf2f((unsigned short)(r1 >> 48));
    w.v8 = bf2f((unsigned short)(v8w & 0xffff));
    return w;
}

__global__ __launch_bounds__(512) void displace_bnsp_mul(
        unsigned short* __restrict__ pre, const unsigned short* __restrict__ a_raw,
        const float* __restrict__ stats, const float* __restrict__ g,
        const float* __restrict__ bb, const float* __restrict__ offsets) {
    __shared__ unsigned short img[128 * 136];   // pre channel image (34.8 KB)
    __shared__ float sc[8];
    __shared__ float s_inv;
    int bc = blockIdx.x;
    int cc = bc & 127;
    // inline displacement params
    float dy = offsets[(cc >> 2) * 2 + 0];
    float dx = offsets[(cc >> 2) * 2 + 1];
    float fy = floorf(dy), fx = floorf(dx);
    float wy = dy - fy, wx = dx - fx;
    int iy = (int)fy, ix = (int)fx;
    float w00 = (1.f - wy) * (1.f - wx);
    float w01 = (1.f - wy) * wx;
    float w10 = wy * (1.f - wx);
    float w11 = wy * wx;
    const float N = 262144.f;
    float mean = stats[cc * 2] / N;
    float var  = stats[cc * 2 + 1] / N - mean * mean;
    float rstd = rsqrtf(var + BN_EPS);
    float scl = rstd * g[cc];
    float shf = bb[cc] - mean * scl;
    unsigned short* pb = pre + (size_t)bc * HWSZ;
    const unsigned short* ab = a_raw + (size_t)bc * HWSZ;
    int t = threadIdx.x;
    uint4 aspr[4];                  // softplus(bn(a)) packed bf16, registers
    float lsum = 0.f;
    #pragma unroll
    for (int i = 0; i < 4; ++i) {
        int px = i * 4096 + t * 8;
        uint4 v = *(const uint4*)(pb + px);
        int y = px >> 7, xx = px & 127;
        *(uint4*)&img[y * 136 + xx] = v;
        uint4 av = *(const uint4*)(ab + px);
        unsigned int au[4] = {av.x, av.y, av.z, av.w};
        unsigned int ou[4];
        #pragma unroll
        for (int k = 0; k < 4; ++k) {
            float lo = softplus_fast(bf2f((unsigned short)(au[k] & 0xffff)) * scl + shf);
            float hi = softplus_fast(bf2f((unsigned short)(au[k] >> 16))    * scl + shf);
            lsum += lo + hi;
            ou[k] = (unsigned int)f2bf(lo) | ((unsigned int)f2bf(hi) << 16);
        }
        aspr[i] = uint4{ou[0], ou[1], ou[2], ou[3]};
    }
    lsum = block_reduce(lsum, sc);      // internal syncthreads covers img writes
    if (t == 0) s_inv = 1.f / lsum;
    __syncthreads();
    float inv = s_inv;
    int s = ix & 7;
    int ix8 = ix - s;
    int sh = (s & 3) * 16;
    bool s4 = s >= 4;
    #pragma unroll
    for (int i = 0; i < 4; ++i) {
        int px = i * 4096 + t * 8;
        int y = px >> 7, x0 = px & 127;
        int yy0 = y + iy, yy1 = yy0 + 1;
        float wA0 = (yy0 >= 0 && yy0 < 128) ? w00 : 0.f;
        float wA1 = (yy0 >= 0 && yy0 < 128) ? w01 : 0.f;
        float wB0 = (yy1 >= 0 && yy1 < 128) ? w10 : 0.f;
        float wB1 = (yy1 >= 0 && yy1 < 128) ? w11 : 0.f;
        int yc0 = min(max(yy0, 0), 127), yc1 = min(max(yy1, 0), 127);
        int w0 = x0 + ix8;
        uint4 z = {0u, 0u, 0u, 0u};
        uint4 qa0 = (w0 >= 0 && w0 <= 120)         ? *(const uint4*)&img[yc0 * 136 + w0]     : z;
        uint4 qa1 = (w0 + 8 >= 0 && w0 + 8 <= 120) ? *(const uint4*)&img[yc0 * 136 + w0 + 8] : z;
        uint4 qb0 = (w0 >= 0 && w0 <= 120)         ? *(const uint4*)&img[yc1 * 136 + w0]     : z;
        uint4 qb1 = (w0 + 8 >= 0 && w0 + 8 <= 120) ? *(const uint4*)&img[yc1 * 136 + w0 + 8] : z;
        Win9 va = extract9(qa0, qa1, s4, sh);
        Win9 vb = extract9(qb0, qb1, s4, sh);
        float dv0 = wA0*va.v0 + wA1*va.v1 + wB0*vb.v0 + wB1*vb.v1;
        float dv1 = wA0*va.v1 + wA1*va.v2 + wB0*vb.v1 + wB1*vb.v2;
        float dv2 = wA0*va.v2 + wA1*va.v3 + wB0*vb.v2 + wB1*vb.v3;
        float dv3 = wA0*va.v3 + wA1*va.v4 + wB0*vb.v3 + wB1*vb.v4;
        float dv4 = wA0*va.v4 + wA1*va.v5 + wB0*vb.v4 + wB1*vb.v5;
        float dv5 = wA0*va.v5 + wA1*va.v6 + wB0*vb.v5 + wB1*vb.v6;
        float dv6 = wA0*va.v6 + wA1*va.v7 + wB0*vb.v6 + wB1*vb.v7;
        float dv7 = wA0*va.v7 + wA1*va.v8 + wB0*vb.v7 + wB1*vb.v8;
        unsigned int au[4] = {aspr[i].x, aspr[i].y, aspr[i].z, aspr[i].w};
        float a0 = bf2f((unsigned short)(au[0] & 0xffff)) * inv;
        float a1 = bf2f((unsigned short)(au[0] >> 16)) * inv;
        float a2 = bf2f((unsigned short)(au[1] & 0xffff)) * inv;
        float a3 = bf2f((unsigned short)(au[1] >> 16)) * inv;
        float a4 = bf2f((unsigned short)(au[2] & 0xffff)) * inv;
        float a5 = bf2f((unsigned short)(au[2] >> 16)) * inv;
        float a6 = bf2f((unsigned short)(au[3] & 0xffff)) * inv;
        float a7 = bf2f((unsigned short)(au[3] >> 16)) * inv;
        uint4 o;
        o.x = (unsigned int)f2bf(dv0 * a0) | ((unsigned int)f2bf(dv1 * a1) << 16);
        o.y = (unsigned int)f2bf(dv2 * a2) | ((unsigned int)f2bf(dv3 * a3) << 16);
        o.z = (unsigned int)f2bf(dv4 * a4) | ((unsigned int)f2bf(dv5 * a5) << 16);
        o.w = (unsigned int)f2bf(dv6 * a6) | ((unsigned int)f2bf(dv7 * a7) << 16);
        *(uint4*)(pb + px) = o;
    }
}

// ---------------- MFMA conv 128->64 + bias + skip -> skipS ----------------
__global__ __launch_bounds__(256) void conv_post_mfma(
        const unsigned short* __restrict__ m, const float* __restrict__ post_w,
        const float* __restrict__ post_b, const float* __restrict__ x,
        unsigned short* __restrict__ skipS) {
    __shared__ unsigned short mT[128 * 128];  // byte = px*256 + ((c*2) ^ ((px&7)<<4))
    int t = threadIdx.x;
    int P0 = blockIdx.x * 128;
    int b = P0 >> 14, poff = P0 & 16383;
    int cl = t & 31, q = t >> 5;
    #pragma unroll
    for (int pass = 0; pass < 4; ++pass) {
        int c = cl + pass * 32;
        const unsigned short* mrow = m + ((size_t)b * CD + c) * HWSZ + poff;
        #pragma unroll
        for (int h = 0; h < 2; ++h) {
            int px0 = h * 64 + q * 8;
            uint4 v = *(const uint4*)(mrow + px0);
            unsigned int u[4] = {v.x, v.y, v.z, v.w};
            #pragma unroll
            for (int j = 0; j < 8; ++j) {
                unsigned short val = (unsigned short)((u[j >> 1] >> ((j & 1) * 16)) & 0xffff);
                int byteoff = (px0 + j) * 256 + ((c * 2) ^ (j << 4));
                *(unsigned short*)((char*)mT + byteoff) = val;
            }
        }
    }
    __syncthreads();
    int ln = t & 63, wv = t >> 6;
    int o0 = (wv >> 1) * 32;
    int ph = (wv & 1) * 64;
    short8x aw[2][4];
    #pragma unroll
    for (int oi = 0; oi < 2; ++oi)
        #pragma unroll
        for (int kk = 0; kk < 4; ++kk) {
            int o = o0 + oi * 16 + (ln & 15);
            aw[oi][kk] = cvt_w8(post_w + o * 128 + kk * 32 + (ln >> 4) * 8);
        }
    floatx4 acc[2][4];
    #pragma unroll
    for (int oi = 0; oi < 2; ++oi)
        #pragma unroll
        for (int pi = 0; pi < 4; ++pi) acc[oi][pi] = floatx4{0.f, 0.f, 0.f, 0.f};
    #pragma unroll
    for (int kk = 0; kk < 4; ++kk)
        #pragma unroll
        for (int pi = 0; pi < 4; ++pi) {
            int px = ph + pi * 16 + (ln & 15);
            int cb = kk * 64 + (ln >> 4) * 16;
            short8x bf = *(const short8x*)((const char*)mT + px * 256 + (cb ^ ((px & 7) << 4)));
            #pragma unroll
            for (int oi = 0; oi < 2; ++oi)
                acc[oi][pi] = __builtin_amdgcn_mfma_f32_16x16x32_bf16(aw[oi][kk], bf, acc[oi][pi], 0, 0, 0);
        }
    #pragma unroll
    for (int oi = 0; oi < 2; ++oi) {
        float4 b4 = *(const float4*)(post_b + o0 + oi * 16 + (ln >> 4) * 4);
        float bb[4] = {b4.x, b4.y, b4.z, b4.w};
        #pragma unroll
        for (int pi = 0; pi < 4; ++pi) {
            int pxg = poff + ph + pi * 16 + (ln & 15);
            #pragma unroll
            for (int r = 0; r < 4; ++r) {
                int o = o0 + oi * 16 + (ln >> 4) * 4 + r;
                float val = acc[oi][pi][r] + bb[r] + x[((size_t)b * COUT + o) * HWSZ + pxg];
                skipS[((size_t)b * CD + o) * HWSZ + pxg] = f2bf(val);
            }
        }
    }
}

// ---------------- final BN + ReLU: skipS bf16 -> d_out fp32 ----------------
__global__ __launch_bounds__(256) void bn_relu_out(
        const unsigned short* __restrict__ skipS, float* __restrict__ out,
        const float* __restrict__ stats, const float* __restrict__ g,
        const float* __restrict__ bb) {
    const float N = 262144.f;
    int t = threadIdx.x;
    #pragma unroll
    for (int k = 0; k < 4; ++k) {
        size_t gidx = (size_t)blockIdx.x * 1024 + k * 256 + t;  // 8-elem index
        size_t e = gidx * 8;
        int b = (int)(e >> 20);
        int c = (int)(e >> 14) & 63;
        int px = (int)(e & 16383);
        float mean = stats[c * 2] / N;
        float rstd = rsqrtf(stats[c * 2 + 1] / N - mean * mean + BN_EPS);
        float gc = g[c], bbc = bb[c];
        uint4 v = *(const uint4*)(skipS + ((size_t)b * CD + c) * HWSZ + px);
        unsigned int u[4] = {v.x, v.y, v.z, v.w};
        float4 o0, o1;
        float* op[8] = {&o0.x, &o0.y, &o0.z, &o0.w, &o1.x, &o1.y, &o1.z, &o1.w};
        #pragma unroll
        for (int j = 0; j < 8; ++j) {
            float val = bf2f((unsigned short)((u[j >> 1] >> ((j & 1) * 16)) & 0xffff));
            *op[j] = fmaxf((val - mean) * rstd * gc + bbc, 0.f);
        }
        *(float4*)(out + e) = o0;
        *(float4*)(out + e + 4) = o1;
    }
}

extern "C" void kernel_launch(void* const* d_in, const int* in_sizes, int n_in,
                              void* d_out, int out_size, void* d_ws, size_t ws_size,
                              hipStream_t stream) {
    const float* x          = (const float*)d_in[0];
    const float* pre_w      = (const float*)d_in[1];
    const float* pre_b      = (const float*)d_in[2];
    const float* post_w     = (const float*)d_in[3];
    const float* post_b     = (const float*)d_in[4];
    const float* atten_w    = (const float*)d_in[5];
    const float* atten_b    = (const float*)d_in[6];
    const float* atten_bn_g = (const float*)d_in[7];
    const float* atten_bn_b = (const float*)d_in[8];
    const float* offsets    = (const float*)d_in[9];
    const float* bn_g       = (const float*)d_in[10];
    const float* bn_b       = (const float*)d_in[11];
    float* out = (float*)d_out;
    float* ws  = (float*)d_ws;

    if (ws_size < WS_TOTAL_BYTES) return;

    float* a_stats = ws + WS_ASTAT;
    float* o_stats = ws + WS_OSTAT;
    unsigned short* big   = (unsigned short*)(ws + WS_BIG);  // out_pre -> m -> skipS
    unsigned short* a_buf = (unsigned short*)d_out;          // a_raw (bf16)

    hipMemsetAsync((void*)a_stats, 0, 384 * sizeof(float), stream);

    conv_pre_mfma<<<1024, 256, 0, stream>>>(x, pre_w, atten_w, pre_b, atten_b, big, a_buf);
    chan_stats_bf16<<<dim3(128, 16), 256, 0, stream>>>(a_buf, a_stats);
    displace_bnsp_mul<<<2048, 512, 0, stream>>>(big, a_buf, a_stats, atten_bn_g, atten_bn_b, offsets);
    conv_post_mfma<<<2048, 256, 0, stream>>>(big, post_w, post_b, x, big);
    chan_stats_bf16<<<dim3(64, 16), 256, 0, stream>>>(big, o_stats);
    bn_relu_out<<<2048, 256, 0, stream>>>(big, out, o_stats, bn_g, bn_b);
}

// Round 13
// 162.276 us; speedup vs baseline: 1.1437x; 1.0116x over previous
//
#include <hip/hip_runtime.h>

#define HWSZ   16384
#define CIN    64
#define CD     128
#define COUT   64
#define BN_EPS 1e-5f

typedef __attribute__((ext_vector_type(8))) short short8x;
typedef __attribute__((ext_vector_type(4))) float floatx4;

// ws layout (float offsets):
//  25344 : a_stats[256]
//  25600 : o_stats[128]
//  32768 : big region (64 MiB): out_pre (slots 0..127) -> m (in place) -> skipS (slots 0..63)
// d_out: a_raw (bf16) -> dead -> final fp32 output
#define WS_ASTAT 25344
#define WS_OSTAT 25600
#define WS_BIG   32768
#define WS_TOTAL_BYTES ((size_t)(32768 + 16777216) * 4)

__device__ __forceinline__ unsigned short f2bf(float f) {
    unsigned int u = __float_as_uint(f);
    u += 0x7fff + ((u >> 16) & 1);
    return (unsigned short)(u >> 16);
}
__device__ __forceinline__ float bf2f(unsigned short s) {
    return __uint_as_float(((unsigned int)s) << 16);
}
__device__ __forceinline__ float softplus_fast(float x) {
    return fmaxf(x, 0.f) + __logf(1.f + __expf(-fabsf(x)));
}
// works for 4 or 8 waves (sc must be float[8]); valid in thread 0
__device__ __forceinline__ float block_reduce(float v, float* sc) {
    #pragma unroll
    for (int off = 32; off >= 1; off >>= 1) v += __shfl_xor(v, off, 64);
    int wv = threadIdx.x >> 6, ln = threadIdx.x & 63;
    int nw = blockDim.x >> 6;
    if (ln == 0) sc[wv] = v;
    __syncthreads();
    float r = ((int)threadIdx.x < nw) ? sc[threadIdx.x] : 0.f;
    r += __shfl_xor(r, 1, 64);
    r += __shfl_xor(r, 2, 64);
    r += __shfl_xor(r, 4, 64);
    return r;
}

__device__ __forceinline__ short8x cvt_w8(const float* src) {
    float4 f0 = *(const float4*)(src);
    float4 f1 = *(const float4*)(src + 4);
    short8x w;
    w[0] = (short)f2bf(f0.x); w[1] = (short)f2bf(f0.y);
    w[2] = (short)f2bf(f0.z); w[3] = (short)f2bf(f0.w);
    w[4] = (short)f2bf(f1.x); w[5] = (short)f2bf(f1.y);
    w[6] = (short)f2bf(f1.z); w[7] = (short)f2bf(f1.w);
    return w;
}

// ---------------- conv_pre helpers ----------------
#define OBPAD 68   // row stride (ushorts)

__device__ __forceinline__ void pre_write_lds(unsigned short* wbuf, int c, int wv,
                                              const float4 ld[4]) {
    #pragma unroll
    for (int k = 0; k < 4; ++k) {
        int px = wv * 16 + k * 4;
        wbuf[(px + 0) * 72 + c] = f2bf(ld[k].x);
        wbuf[(px + 1) * 72 + c] = f2bf(ld[k].y);
        wbuf[(px + 2) * 72 + c] = f2bf(ld[k].z);
        wbuf[(px + 3) * 72 + c] = f2bf(ld[k].w);
    }
}

// swapped-operand compute: D[px][o]; results staged into ob[256][OBPAD]
__device__ __forceinline__ void pre_compute_tile(
        const unsigned short* buf, unsigned short* ob, int ln, int wv,
        const short8x wfrag[4][2], const float bv[4]) {
    floatx4 acc[4][4];
    #pragma unroll
    for (int oi = 0; oi < 4; ++oi)
        #pragma unroll
        for (int pi = 0; pi < 4; ++pi)
            acc[oi][pi] = floatx4{bv[oi], bv[oi], bv[oi], bv[oi]};
    #pragma unroll
    for (int kk = 0; kk < 2; ++kk)
        #pragma unroll
        for (int pi = 0; pi < 4; ++pi) {
            short8x xfrag = *(const short8x*)((const char*)buf +
                    (pi * 16 + (ln & 15)) * 144 + (kk * 32 + (ln >> 4) * 8) * 2);
            #pragma unroll
            for (int oi = 0; oi < 4; ++oi)
                acc[oi][pi] = __builtin_amdgcn_mfma_f32_16x16x32_bf16(
                        xfrag, wfrag[oi][kk], acc[oi][pi], 0, 0, 0);
        }
    #pragma unroll
    for (int oi = 0; oi < 4; ++oi) {
        int row = wv * 64 + oi * 16 + (ln & 15);
        #pragma unroll
        for (int pi = 0; pi < 4; ++pi) {
            int px = pi * 16 + (ln >> 4) * 4;
            ushort4 v;
            v.x = f2bf(acc[oi][pi][0]); v.y = f2bf(acc[oi][pi][1]);
            v.z = f2bf(acc[oi][pi][2]); v.w = f2bf(acc[oi][pi][3]);
            *(ushort4*)&ob[row * OBPAD + px] = v;
        }
    }
}

// ---------------- K1: MFMA conv1x1 (pre + atten), depth-2 pipelined ----------------
__global__ __launch_bounds__(256) void conv_pre_mfma(
        const float* __restrict__ x, const float* __restrict__ pre_w,
        const float* __restrict__ atten_w,
        const float* __restrict__ pre_b, const float* __restrict__ atten_b,
        unsigned short* __restrict__ out_pre, unsigned short* __restrict__ a_out) {
    __shared__ unsigned short xT[2][64 * 72];      // input staging (2 x 9 KB)
    __shared__ unsigned short ob[256 * OBPAD];     // output staging (34 KB)
    int t = threadIdx.x;
    int wv = t >> 6, ln = t & 63;
    int b = blockIdx.x >> 6;
    int poff = (blockIdx.x & 63) << 8;             // 256-px super-tile
    const float* xg = x + (size_t)b * CIN * HWSZ + poff;
    int c = ln;

    int o0 = wv * 64;
    short8x wfrag[4][2];
    #pragma unroll
    for (int oi = 0; oi < 4; ++oi)
        #pragma unroll
        for (int kk = 0; kk < 2; ++kk) {
            int row = o0 + oi * 16 + (ln & 15);
            int kcol = kk * 32 + (ln >> 4) * 8;
            const float* wsrc = (row < 128) ? (pre_w + row * 64)
                                            : (atten_w + (row - 128) * 64);
            wfrag[oi][kk] = cvt_w8(wsrc + kcol);
        }
    float bv[4];
    #pragma unroll
    for (int oi = 0; oi < 4; ++oi) {
        int og = o0 + oi * 16;
        bv[oi] = (og < 128) ? pre_b[og + (ln & 15)] : atten_b[og - 128 + (ln & 15)];
    }

    float4 lda[4], ldb[4];
    #pragma unroll
    for (int k = 0; k < 4; ++k)
        lda[k] = *(const float4*)(xg + (size_t)c * HWSZ + 0 * 64 + wv * 16 + k * 4);
    pre_write_lds(xT[0], c, wv, lda);
    #pragma unroll
    for (int k = 0; k < 4; ++k)
        lda[k] = *(const float4*)(xg + (size_t)c * HWSZ + 1 * 64 + wv * 16 + k * 4);
    __syncthreads();

    #pragma unroll
    for (int tt = 0; tt < 4; ++tt) {
        if (tt == 0) {
            #pragma unroll
            for (int k = 0; k < 4; ++k)
                ldb[k] = *(const float4*)(xg + (size_t)c * HWSZ + 2 * 64 + wv * 16 + k * 4);
        } else if (tt == 1) {
            #pragma unroll
            for (int k = 0; k < 4; ++k)
                lda[k] = *(const float4*)(xg + (size_t)c * HWSZ + 3 * 64 + wv * 16 + k * 4);
        }
        pre_compute_tile(xT[tt & 1], ob, ln, wv, wfrag, bv);
        if (tt == 0)      pre_write_lds(xT[1], c, wv, lda);
        else if (tt == 1) pre_write_lds(xT[0], c, wv, ldb);
        else if (tt == 2) pre_write_lds(xT[1], c, wv, lda);
        __syncthreads();
        int ptile = poff + tt * 64;
        #pragma unroll
        for (int j = 0; j < 8; ++j) {
            int row = j * 32 + (t >> 3);
            int px  = (t & 7) * 8;
            uint4 v = *(const uint4*)&ob[row * OBPAD + px];
            unsigned short* dst = (row < 128) ? out_pre : a_out;
            int o = row & 127;
            *(uint4*)(dst + ((size_t)b * CD + o) * HWSZ + ptile + px) = v;
        }
        __syncthreads();
    }
}

// ---------------- per-channel sum/sumsq over bf16 src ----------------
__global__ __launch_bounds__(256) void chan_stats_bf16(
        const unsigned short* __restrict__ src, float* __restrict__ stats) {
    __shared__ float sc1[8], sc2[8];
    int c = blockIdx.x, b = blockIdx.y;
    const unsigned short* base = src + ((size_t)b * CD + c) * HWSZ;
    int t = threadIdx.x;
    float sum = 0.f, sq = 0.f;
    #pragma unroll
    for (int i = 0; i < 8; ++i) {
        uint4 v = *(const uint4*)(base + i * 2048 + t * 8);
        unsigned int u[4] = {v.x, v.y, v.z, v.w};
        #pragma unroll
        for (int k = 0; k < 4; ++k) {
            float lo = bf2f((unsigned short)(u[k] & 0xffff));
            float hi = bf2f((unsigned short)(u[k] >> 16));
            sum += lo + hi;
            sq  += lo * lo + hi * hi;
        }
    }
    sum = block_reduce(sum, sc1);
    __syncthreads();
    sq = block_reduce(sq, sc2);
    if (t == 0) {
        atomicAdd(&stats[c * 2 + 0], sum);
        atomicAdd(&stats[c * 2 + 1], sq);
    }
}

// ---------------- fused: BN+softplus (f32 regs) + spat-reduce + displace + mul ----------------
struct Win9 { float v0,v1,v2,v3,v4,v5,v6,v7,v8; };
__device__ __forceinline__ Win9 extract9(uint4 qa, uint4 qb, bool s4, int sh) {
    unsigned long long A0 = ((unsigned long long)qa.y << 32) | qa.x;
    unsigned long long A1 = ((unsigned long long)qa.w << 32) | qa.z;
    unsigned long long A2 = ((unsigned long long)qb.y << 32) | qb.x;
    unsigned long long A3 = ((unsigned long long)qb.w << 32) | qb.z;
    unsigned long long B0 = s4 ? A1 : A0;
    unsigned long long B1 = s4 ? A2 : A1;
    unsigned long long B2 = s4 ? A3 : A2;
    unsigned long long r0 = sh ? ((B0 >> sh) | (B1 << (64 - sh))) : B0;
    unsigned long long r1 = sh ? ((B1 >> sh) | (B2 << (64 - sh))) : B1;
    unsigned int v8w = (unsigned int)(sh ? (B2 >> sh) : B2);
    Win9 w;
    w.v0 = bf2f((unsigned short)(r0 >>  0)); w.v1 = bf2f((unsigned short)(r0 >> 16));
    w.v2 = bf2f((unsigned short)(r0 >> 32)); w.v3 = bf2f((unsigned short)(r0 >> 48));
    w.v4 = bf2f((unsigned short)(r1 >>  0)); w.v5 = bf2f((unsigned short)(r1 >> 16));
    w.v6 = bf2f((unsigned short)(r1 >> 32)); w.v7 = bf2f((unsigned short)(r1 >> 48));
    w.v8 = bf2f((unsigned short)(v8w & 0xffff));
    return w;
}

__global__ __launch_bounds__(512) void displace_bnsp_mul(
        unsigned short* __restrict__ pre, const unsigned short* __restrict__ a_raw,
        const float* __restrict__ stats, const float* __restrict__ g,
        const float* __restrict__ bb, const float* __restrict__ offsets) {
    __shared__ unsigned short img[128 * 136];   // pre channel image (34.8 KB)
    __shared__ float sc[8];
    __shared__ float s_inv;
    int bc = blockIdx.x;
    int cc = bc & 127;
    float dy = offsets[(cc >> 2) * 2 + 0];
    float dx = offsets[(cc >> 2) * 2 + 1];
    float fy = floorf(dy), fx = floorf(dx);
    float wy = dy - fy, wx = dx - fx;
    int iy = (int)fy, ix = (int)fx;
    float w00 = (1.f - wy) * (1.f - wx);
    float w01 = (1.f - wy) * wx;
    float w10 = wy * (1.f - wx);
    float w11 = wy * wx;
    const float N = 262144.f;
    float mean = stats[cc * 2] / N;
    float var  = stats[cc * 2 + 1] / N - mean * mean;
    float rstd = rsqrtf(var + BN_EPS);
    float scl = rstd * g[cc];
    float shf = bb[cc] - mean * scl;
    unsigned short* pb = pre + (size_t)bc * HWSZ;
    const unsigned short* ab = a_raw + (size_t)bc * HWSZ;
    int t = threadIdx.x;
    float aspf[4][8];               // softplus(bn(a)) in f32 REGISTERS (no bf16 round-trip)
    float lsum = 0.f;
    #pragma unroll
    for (int i = 0; i < 4; ++i) {
        int px = i * 4096 + t * 8;
        uint4 v = *(const uint4*)(pb + px);
        int y = px >> 7, xx = px & 127;
        *(uint4*)&img[y * 136 + xx] = v;
        uint4 av = *(const uint4*)(ab + px);
        unsigned int au[4] = {av.x, av.y, av.z, av.w};
        #pragma unroll
        for (int k = 0; k < 4; ++k) {
            float lo = softplus_fast(bf2f((unsigned short)(au[k] & 0xffff)) * scl + shf);
            float hi = softplus_fast(bf2f((unsigned short)(au[k] >> 16))    * scl + shf);
            lsum += lo + hi;
            aspf[i][2 * k]     = lo;
            aspf[i][2 * k + 1] = hi;
        }
    }
    lsum = block_reduce(lsum, sc);      // internal syncthreads covers img writes
    if (t == 0) s_inv = 1.f / lsum;
    __syncthreads();
    float inv = s_inv;
    // fold 1/spat into the bilinear weights: m = (inv*dv) * a
    w00 *= inv; w01 *= inv; w10 *= inv; w11 *= inv;
    int s = ix & 7;
    int ix8 = ix - s;
    int sh = (s & 3) * 16;
    bool s4 = s >= 4;
    #pragma unroll
    for (int i = 0; i < 4; ++i) {
        int px = i * 4096 + t * 8;
        int y = px >> 7, x0 = px & 127;
        int yy0 = y + iy, yy1 = yy0 + 1;
        float wA0 = (yy0 >= 0 && yy0 < 128) ? w00 : 0.f;
        float wA1 = (yy0 >= 0 && yy0 < 128) ? w01 : 0.f;
        float wB0 = (yy1 >= 0 && yy1 < 128) ? w10 : 0.f;
        float wB1 = (yy1 >= 0 && yy1 < 128) ? w11 : 0.f;
        int yc0 = min(max(yy0, 0), 127), yc1 = min(max(yy1, 0), 127);
        int w0 = x0 + ix8;
        uint4 z = {0u, 0u, 0u, 0u};
        uint4 qa0 = (w0 >= 0 && w0 <= 120)         ? *(const uint4*)&img[yc0 * 136 + w0]     : z;
        uint4 qa1 = (w0 + 8 >= 0 && w0 + 8 <= 120) ? *(const uint4*)&img[yc0 * 136 + w0 + 8] : z;
        uint4 qb0 = (w0 >= 0 && w0 <= 120)         ? *(const uint4*)&img[yc1 * 136 + w0]     : z;
        uint4 qb1 = (w0 + 8 >= 0 && w0 + 8 <= 120) ? *(const uint4*)&img[yc1 * 136 + w0 + 8] : z;
        Win9 va = extract9(qa0, qa1, s4, sh);
        Win9 vb = extract9(qb0, qb1, s4, sh);
        float m0 = (wA0*va.v0 + wA1*va.v1 + wB0*vb.v0 + wB1*vb.v1) * aspf[i][0];
        float m1 = (wA0*va.v1 + wA1*va.v2 + wB0*vb.v1 + wB1*vb.v2) * aspf[i][1];
        float m2 = (wA0*va.v2 + wA1*va.v3 + wB0*vb.v2 + wB1*vb.v3) * aspf[i][2];
        float m3 = (wA0*va.v3 + wA1*va.v4 + wB0*vb.v3 + wB1*vb.v4) * aspf[i][3];
        float m4 = (wA0*va.v4 + wA1*va.v5 + wB0*vb.v4 + wB1*vb.v5) * aspf[i][4];
        float m5 = (wA0*va.v5 + wA1*va.v6 + wB0*vb.v5 + wB1*vb.v6) * aspf[i][5];
        float m6 = (wA0*va.v6 + wA1*va.v7 + wB0*vb.v6 + wB1*vb.v7) * aspf[i][6];
        float m7 = (wA0*va.v7 + wA1*va.v8 + wB0*vb.v7 + wB1*vb.v8) * aspf[i][7];
        uint4 o;
        o.x = (unsigned int)f2bf(m0) | ((unsigned int)f2bf(m1) << 16);
        o.y = (unsigned int)f2bf(m2) | ((unsigned int)f2bf(m3) << 16);
        o.z = (unsigned int)f2bf(m4) | ((unsigned int)f2bf(m5) << 16);
        o.w = (unsigned int)f2bf(m6) | ((unsigned int)f2bf(m7) << 16);
        *(uint4*)(pb + px) = o;
    }
}

// ---------------- MFMA conv 128->64 + bias + skip -> skipS ----------------
__global__ __launch_bounds__(256) void conv_post_mfma(
        const unsigned short* __restrict__ m, const float* __restrict__ post_w,
        const float* __restrict__ post_b, const float* __restrict__ x,
        unsigned short* __restrict__ skipS) {
    __shared__ unsigned short mT[128 * 128];  // byte = px*256 + ((c*2) ^ ((px&7)<<4))
    int t = threadIdx.x;
    int P0 = blockIdx.x * 128;
    int b = P0 >> 14, poff = P0 & 16383;
    int cl = t & 31, q = t >> 5;
    #pragma unroll
    for (int pass = 0; pass < 4; ++pass) {
        int c = cl + pass * 32;
        const unsigned short* mrow = m + ((size_t)b * CD + c) * HWSZ + poff;
        #pragma unroll
        for (int h = 0; h < 2; ++h) {
            int px0 = h * 64 + q * 8;
            uint4 v = *(const uint4*)(mrow + px0);
            unsigned int u[4] = {v.x, v.y, v.z, v.w};
            #pragma unroll
            for (int j = 0; j < 8; ++j) {
                unsigned short val = (unsigned short)((u[j >> 1] >> ((j & 1) * 16)) & 0xffff);
                int byteoff = (px0 + j) * 256 + ((c * 2) ^ (j << 4));
                *(unsigned short*)((char*)mT + byteoff) = val;
            }
        }
    }
    __syncthreads();
    int ln = t & 63, wv = t >> 6;
    int o0 = (wv >> 1) * 32;
    int ph = (wv & 1) * 64;
    short8x aw[2][4];
    #pragma unroll
    for (int oi = 0; oi < 2; ++oi)
        #pragma unroll
        for (int kk = 0; kk < 4; ++kk) {
            int o = o0 + oi * 16 + (ln & 15);
            aw[oi][kk] = cvt_w8(post_w + o * 128 + kk * 32 + (ln >> 4) * 8);
        }
    floatx4 acc[2][4];
    #pragma unroll
    for (int oi = 0; oi < 2; ++oi)
        #pragma unroll
        for (int pi = 0; pi < 4; ++pi) acc[oi][pi] = floatx4{0.f, 0.f, 0.f, 0.f};
    #pragma unroll
    for (int kk = 0; kk < 4; ++kk)
        #pragma unroll
        for (int pi = 0; pi < 4; ++pi) {
            int px = ph + pi * 16 + (ln & 15);
            int cb = kk * 64 + (ln >> 4) * 16;
            short8x bf = *(const short8x*)((const char*)mT + px * 256 + (cb ^ ((px & 7) << 4)));
            #pragma unroll
            for (int oi = 0; oi < 2; ++oi)
                acc[oi][pi] = __builtin_amdgcn_mfma_f32_16x16x32_bf16(aw[oi][kk], bf, acc[oi][pi], 0, 0, 0);
        }
    #pragma unroll
    for (int oi = 0; oi < 2; ++oi) {
        float4 b4 = *(const float4*)(post_b + o0 + oi * 16 + (ln >> 4) * 4);
        float bb[4] = {b4.x, b4.y, b4.z, b4.w};
        #pragma unroll
        for (int pi = 0; pi < 4; ++pi) {
            int pxg = poff + ph + pi * 16 + (ln & 15);
            #pragma unroll
            for (int r = 0; r < 4; ++r) {
                int o = o0 + oi * 16 + (ln >> 4) * 4 + r;
                float val = acc[oi][pi][r] + bb[r] + x[((size_t)b * COUT + o) * HWSZ + pxg];
                skipS[((size_t)b * CD + o) * HWSZ + pxg] = f2bf(val);
            }
        }
    }
}

// ---------------- final BN + ReLU: skipS bf16 -> d_out fp32 ----------------
__global__ __launch_bounds__(256) void bn_relu_out(
        const unsigned short* __restrict__ skipS, float* __restrict__ out,
        const float* __restrict__ stats, const float* __restrict__ g,
        const float* __restrict__ bb) {
    const float N = 262144.f;
    int t = threadIdx.x;
    #pragma unroll
    for (int k = 0; k < 4; ++k) {
        size_t gidx = (size_t)blockIdx.x * 1024 + k * 256 + t;  // 8-elem index
        size_t e = gidx * 8;
        int b = (int)(e >> 20);
        int c = (int)(e >> 14) & 63;
        int px = (int)(e & 16383);
        float mean = stats[c * 2] / N;
        float rstd = rsqrtf(stats[c * 2 + 1] / N - mean * mean + BN_EPS);
        float gc = g[c], bbc = bb[c];
        uint4 v = *(const uint4*)(skipS + ((size_t)b * CD + c) * HWSZ + px);
        unsigned int u[4] = {v.x, v.y, v.z, v.w};
        float4 o0, o1;
        float* op[8] = {&o0.x, &o0.y, &o0.z, &o0.w, &o1.x, &o1.y, &o1.z, &o1.w};
        #pragma unroll
        for (int j = 0; j < 8; ++j) {
            float val = bf2f((unsigned short)((u[j >> 1] >> ((j & 1) * 16)) & 0xffff));
            *op[j] = fmaxf((val - mean) * rstd * gc + bbc, 0.f);
        }
        *(float4*)(out + e) = o0;
        *(float4*)(out + e + 4) = o1;
    }
}

extern "C" void kernel_launch(void* const* d_in, const int* in_sizes, int n_in,
                              void* d_out, int out_size, void* d_ws, size_t ws_size,
                              hipStream_t stream) {
    const float* x          = (const float*)d_in[0];
    const float* pre_w      = (const float*)d_in[1];
    const float* pre_b      = (const float*)d_in[2];
    const float* post_w     = (const float*)d_in[3];
    const float* post_b     = (const float*)d_in[4];
    const float* atten_w    = (const float*)d_in[5];
    const float* atten_b    = (const float*)d_in[6];
    const float* atten_bn_g = (const float*)d_in[7];
    const float* atten_bn_b = (const float*)d_in[8];
    const float* offsets    = (const float*)d_in[9];
    const float* bn_g       = (const float*)d_in[10];
    const float* bn_b       = (const float*)d_in[11];
    float* out = (float*)d_out;
    float* ws  = (float*)d_ws;

    if (ws_size < WS_TOTAL_BYTES) return;

    float* a_stats = ws + WS_ASTAT;
    float* o_stats = ws + WS_OSTAT;
    unsigned short* big   = (unsigned short*)(ws + WS_BIG);  // out_pre -> m -> skipS
    unsigned short* a_buf = (unsigned short*)d_out;          // a_raw (bf16)

    hipMemsetAsync((void*)a_stats, 0, 384 * sizeof(float), stream);

    conv_pre_mfma<<<1024, 256, 0, stream>>>(x, pre_w, atten_w, pre_b, atten_b, big, a_buf);
    chan_stats_bf16<<<dim3(128, 16), 256, 0, stream>>>(a_buf, a_stats);
    displace_bnsp_mul<<<2048, 512, 0, stream>>>(big, a_buf, a_stats, atten_bn_g, atten_bn_b, offsets);
    conv_post_mfma<<<2048, 256, 0, stream>>>(big, post_w, post_b, x, big);
    chan_stats_bf16<<<dim3(64, 16), 256, 0, stream>>>(big, o_stats);
    bn_relu_out<<<2048, 256, 0, stream>>>(big, out, o_stats, bn_g, bn_b);
}

// Round 14
// 152.733 us; speedup vs baseline: 1.2152x; 1.0625x over previous
//
#include <hip/hip_runtime.h>

#define HWSZ   16384
#define CIN    64
#define CD     128
#define COUT   64
#define BN_EPS 1e-5f

typedef __attribute__((ext_vector_type(8))) short short8x;
typedef __attribute__((ext_vector_type(4))) float floatx4;

// ws layout (float offsets):
//  25344 : a_stats8[8][256]  (8 replicated slots, sum/sumsq per Cd channel)
//  27392 : o_stats[128]
//  32768 : big region (64 MiB): out_pre (slots 0..127) -> m (in place) -> skipS (slots 0..63)
// d_out: a_raw (bf16) -> dead -> final fp32 output
#define WS_ASTAT 25344
#define WS_OSTAT 27392
#define WS_BIG   32768
#define WS_TOTAL_BYTES ((size_t)(32768 + 16777216) * 4)

__device__ __forceinline__ unsigned short f2bf(float f) {
    unsigned int u = __float_as_uint(f);
    u += 0x7fff + ((u >> 16) & 1);
    return (unsigned short)(u >> 16);
}
__device__ __forceinline__ float bf2f(unsigned short s) {
    return __uint_as_float(((unsigned int)s) << 16);
}
__device__ __forceinline__ float softplus_fast(float x) {
    return fmaxf(x, 0.f) + __logf(1.f + __expf(-fabsf(x)));
}
// works for 4 or 8 waves (sc must be float[8]); valid in thread 0
__device__ __forceinline__ float block_reduce(float v, float* sc) {
    #pragma unroll
    for (int off = 32; off >= 1; off >>= 1) v += __shfl_xor(v, off, 64);
    int wv = threadIdx.x >> 6, ln = threadIdx.x & 63;
    int nw = blockDim.x >> 6;
    if (ln == 0) sc[wv] = v;
    __syncthreads();
    float r = ((int)threadIdx.x < nw) ? sc[threadIdx.x] : 0.f;
    r += __shfl_xor(r, 1, 64);
    r += __shfl_xor(r, 2, 64);
    r += __shfl_xor(r, 4, 64);
    return r;
}

__device__ __forceinline__ short8x cvt_w8(const float* src) {
    float4 f0 = *(const float4*)(src);
    float4 f1 = *(const float4*)(src + 4);
    short8x w;
    w[0] = (short)f2bf(f0.x); w[1] = (short)f2bf(f0.y);
    w[2] = (short)f2bf(f0.z); w[3] = (short)f2bf(f0.w);
    w[4] = (short)f2bf(f1.x); w[5] = (short)f2bf(f1.y);
    w[6] = (short)f2bf(f1.z); w[7] = (short)f2bf(f1.w);
    return w;
}

// ---------------- conv_pre helpers ----------------
#define OBPAD 68   // row stride (ushorts)

__device__ __forceinline__ void pre_write_lds(unsigned short* wbuf, int c, int wv,
                                              const float4 ld[4]) {
    #pragma unroll
    for (int k = 0; k < 4; ++k) {
        int px = wv * 16 + k * 4;
        wbuf[(px + 0) * 72 + c] = f2bf(ld[k].x);
        wbuf[(px + 1) * 72 + c] = f2bf(ld[k].y);
        wbuf[(px + 2) * 72 + c] = f2bf(ld[k].z);
        wbuf[(px + 3) * 72 + c] = f2bf(ld[k].w);
    }
}

// swapped-operand compute: D[px][o]; results staged into ob[256][OBPAD]
__device__ __forceinline__ void pre_compute_tile(
        const unsigned short* buf, unsigned short* ob, int ln, int wv,
        const short8x wfrag[4][2], const float bv[4]) {
    floatx4 acc[4][4];
    #pragma unroll
    for (int oi = 0; oi < 4; ++oi)
        #pragma unroll
        for (int pi = 0; pi < 4; ++pi)
            acc[oi][pi] = floatx4{bv[oi], bv[oi], bv[oi], bv[oi]};
    #pragma unroll
    for (int kk = 0; kk < 2; ++kk)
        #pragma unroll
        for (int pi = 0; pi < 4; ++pi) {
            short8x xfrag = *(const short8x*)((const char*)buf +
                    (pi * 16 + (ln & 15)) * 144 + (kk * 32 + (ln >> 4) * 8) * 2);
            #pragma unroll
            for (int oi = 0; oi < 4; ++oi)
                acc[oi][pi] = __builtin_amdgcn_mfma_f32_16x16x32_bf16(
                        xfrag, wfrag[oi][kk], acc[oi][pi], 0, 0, 0);
        }
    #pragma unroll
    for (int oi = 0; oi < 4; ++oi) {
        int row = wv * 64 + oi * 16 + (ln & 15);
        #pragma unroll
        for (int pi = 0; pi < 4; ++pi) {
            int px = pi * 16 + (ln >> 4) * 4;
            ushort4 v;
            v.x = f2bf(acc[oi][pi][0]); v.y = f2bf(acc[oi][pi][1]);
            v.z = f2bf(acc[oi][pi][2]); v.w = f2bf(acc[oi][pi][3]);
            *(ushort4*)&ob[row * OBPAD + px] = v;
        }
    }
}

// ---------------- K1: MFMA conv1x1 (pre + atten) + fused a-stats ----------------
// Stats ride the transpose-store phase: thread owns one channel-row's 8 px per j,
// same row every tile -> register accumulation, one 8-lane shuffle at the end.
__global__ __launch_bounds__(256) void conv_pre_mfma(
        const float* __restrict__ x, const float* __restrict__ pre_w,
        const float* __restrict__ atten_w,
        const float* __restrict__ pre_b, const float* __restrict__ atten_b,
        unsigned short* __restrict__ out_pre, unsigned short* __restrict__ a_out,
        float* __restrict__ a_stats8) {
    __shared__ unsigned short xT[2][64 * 72];      // input staging (2 x 9 KB)
    __shared__ unsigned short ob[256 * OBPAD];     // output staging (34 KB)
    int t = threadIdx.x;
    int wv = t >> 6, ln = t & 63;
    int b = blockIdx.x >> 6;
    int poff = (blockIdx.x & 63) << 8;             // 256-px super-tile
    const float* xg = x + (size_t)b * CIN * HWSZ + poff;
    int c = ln;

    int o0 = wv * 64;
    short8x wfrag[4][2];
    #pragma unroll
    for (int oi = 0; oi < 4; ++oi)
        #pragma unroll
        for (int kk = 0; kk < 2; ++kk) {
            int row = o0 + oi * 16 + (ln & 15);
            int kcol = kk * 32 + (ln >> 4) * 8;
            const float* wsrc = (row < 128) ? (pre_w + row * 64)
                                            : (atten_w + (row - 128) * 64);
            wfrag[oi][kk] = cvt_w8(wsrc + kcol);
        }
    float bv[4];
    #pragma unroll
    for (int oi = 0; oi < 4; ++oi) {
        int og = o0 + oi * 16;
        bv[oi] = (og < 128) ? pre_b[og + (ln & 15)] : atten_b[og - 128 + (ln & 15)];
    }

    float asum[4] = {0.f, 0.f, 0.f, 0.f};   // a-stats accumulators (rows 128..255)
    float asq[4]  = {0.f, 0.f, 0.f, 0.f};

    float4 lda[4], ldb[4];
    #pragma unroll
    for (int k = 0; k < 4; ++k)
        lda[k] = *(const float4*)(xg + (size_t)c * HWSZ + 0 * 64 + wv * 16 + k * 4);
    pre_write_lds(xT[0], c, wv, lda);
    #pragma unroll
    for (int k = 0; k < 4; ++k)
        lda[k] = *(const float4*)(xg + (size_t)c * HWSZ + 1 * 64 + wv * 16 + k * 4);
    __syncthreads();

    #pragma unroll
    for (int tt = 0; tt < 4; ++tt) {
        if (tt == 0) {
            #pragma unroll
            for (int k = 0; k < 4; ++k)
                ldb[k] = *(const float4*)(xg + (size_t)c * HWSZ + 2 * 64 + wv * 16 + k * 4);
        } else if (tt == 1) {
            #pragma unroll
            for (int k = 0; k < 4; ++k)
                lda[k] = *(const float4*)(xg + (size_t)c * HWSZ + 3 * 64 + wv * 16 + k * 4);
        }
        pre_compute_tile(xT[tt & 1], ob, ln, wv, wfrag, bv);
        if (tt == 0)      pre_write_lds(xT[1], c, wv, lda);
        else if (tt == 1) pre_write_lds(xT[0], c, wv, ldb);
        else if (tt == 2) pre_write_lds(xT[1], c, wv, lda);
        __syncthreads();
        int ptile = poff + tt * 64;
        #pragma unroll
        for (int j = 0; j < 8; ++j) {
            int row = j * 32 + (t >> 3);
            int px  = (t & 7) * 8;
            uint4 v = *(const uint4*)&ob[row * OBPAD + px];
            unsigned short* dst = (row < 128) ? out_pre : a_out;
            int o = row & 127;
            *(uint4*)(dst + ((size_t)b * CD + o) * HWSZ + ptile + px) = v;
            if (j >= 4) {   // atten rows: accumulate stats from the staged values
                unsigned int u[4] = {v.x, v.y, v.z, v.w};
                float s = 0.f, q = 0.f;
                #pragma unroll
                for (int k = 0; k < 4; ++k) {
                    float lo = bf2f((unsigned short)(u[k] & 0xffff));
                    float hi = bf2f((unsigned short)(u[k] >> 16));
                    s += lo + hi;
                    q += lo * lo + hi * hi;
                }
                asum[j - 4] += s;
                asq[j - 4]  += q;
            }
        }
        __syncthreads();
    }
    // flush a-stats: reduce over the 8 lanes sharing each row, one atomic per channel
    float* slot = a_stats8 + (blockIdx.x & 7) * 256;
    #pragma unroll
    for (int jj = 0; jj < 4; ++jj) {
        float s = asum[jj], q = asq[jj];
        s += __shfl_xor(s, 1, 64); q += __shfl_xor(q, 1, 64);
        s += __shfl_xor(s, 2, 64); q += __shfl_xor(q, 2, 64);
        s += __shfl_xor(s, 4, 64); q += __shfl_xor(q, 4, 64);
        if ((t & 7) == 0) {
            int o = (jj + 4) * 32 + (t >> 3) - 128;
            atomicAdd(&slot[2 * o],     s);
            atomicAdd(&slot[2 * o + 1], q);
        }
    }
}

// ---------------- per-channel sum/sumsq over bf16 src (o-stats only) ----------------
__global__ __launch_bounds__(256) void chan_stats_bf16(
        const unsigned short* __restrict__ src, float* __restrict__ stats) {
    __shared__ float sc1[8], sc2[8];
    int c = blockIdx.x, b = blockIdx.y;
    const unsigned short* base = src + ((size_t)b * CD + c) * HWSZ;
    int t = threadIdx.x;
    float sum = 0.f, sq = 0.f;
    #pragma unroll
    for (int i = 0; i < 8; ++i) {
        uint4 v = *(const uint4*)(base + i * 2048 + t * 8);
        unsigned int u[4] = {v.x, v.y, v.z, v.w};
        #pragma unroll
        for (int k = 0; k < 4; ++k) {
            float lo = bf2f((unsigned short)(u[k] & 0xffff));
            float hi = bf2f((unsigned short)(u[k] >> 16));
            sum += lo + hi;
            sq  += lo * lo + hi * hi;
        }
    }
    sum = block_reduce(sum, sc1);
    __syncthreads();
    sq = block_reduce(sq, sc2);
    if (t == 0) {
        atomicAdd(&stats[c * 2 + 0], sum);
        atomicAdd(&stats[c * 2 + 1], sq);
    }
}

// ---------------- fused: BN+softplus (f32 regs) + spat-reduce + displace + mul ----------------
struct Win9 { float v0,v1,v2,v3,v4,v5,v6,v7,v8; };
__device__ __forceinline__ Win9 extract9(uint4 qa, uint4 qb, bool s4, int sh) {
    unsigned long long A0 = ((unsigned long long)qa.y << 32) | qa.x;
    unsigned long long A1 = ((unsigned long long)qa.w << 32) | qa.z;
    unsigned long long A2 = ((unsigned long long)qb.y << 32) | qb.x;
    unsigned long long A3 = ((unsigned long long)qb.w << 32) | qb.z;
    unsigned long long B0 = s4 ? A1 : A0;
    unsigned long long B1 = s4 ? A2 : A1;
    unsigned long long B2 = s4 ? A3 : A2;
    unsigned long long r0 = sh ? ((B0 >> sh) | (B1 << (64 - sh))) : B0;
    unsigned long long r1 = sh ? ((B1 >> sh) | (B2 << (64 - sh))) : B1;
    unsigned int v8w = (unsigned int)(sh ? (B2 >> sh) : B2);
    Win9 w;
    w.v0 = bf2f((unsigned short)(r0 >>  0)); w.v1 = bf2f((unsigned short)(r0 >> 16));
    w.v2 = bf2f((unsigned short)(r0 >> 32)); w.v3 = bf2f((unsigned short)(r0 >> 48));
    w.v4 = bf2f((unsigned short)(r1 >>  0)); w.v5 = bf2f((unsigned short)(r1 >> 16));
    w.v6 = bf2f((unsigned short)(r1 >> 32)); w.v7 = bf2f((unsigned short)(r1 >> 48));
    w.v8 = bf2f((unsigned short)(v8w & 0xffff));
    return w;
}

__global__ __launch_bounds__(512) void displace_bnsp_mul(
        unsigned short* __restrict__ pre, const unsigned short* __restrict__ a_raw,
        const float* __restrict__ stats8, const float* __restrict__ g,
        const float* __restrict__ bb, const float* __restrict__ offsets) {
    __shared__ unsigned short img[128 * 136];   // pre channel image (34.8 KB)
    __shared__ float sc[8];
    __shared__ float s_inv;
    int bc = blockIdx.x;
    int cc = bc & 127;
    float dy = offsets[(cc >> 2) * 2 + 0];
    float dx = offsets[(cc >> 2) * 2 + 1];
    float fy = floorf(dy), fx = floorf(dx);
    float wy = dy - fy, wx = dx - fx;
    int iy = (int)fy, ix = (int)fx;
    float w00 = (1.f - wy) * (1.f - wx);
    float w01 = (1.f - wy) * wx;
    float w10 = wy * (1.f - wx);
    float w11 = wy * wx;
    float sum = 0.f, sq = 0.f;
    #pragma unroll
    for (int k = 0; k < 8; ++k) {
        sum += stats8[k * 256 + 2 * cc];
        sq  += stats8[k * 256 + 2 * cc + 1];
    }
    const float N = 262144.f;
    float mean = sum / N;
    float var  = sq / N - mean * mean;
    float rstd = rsqrtf(var + BN_EPS);
    float scl = rstd * g[cc];
    float shf = bb[cc] - mean * scl;
    unsigned short* pb = pre + (size_t)bc * HWSZ;
    const unsigned short* ab = a_raw + (size_t)bc * HWSZ;
    int t = threadIdx.x;
    float aspf[4][8];               // softplus(bn(a)) in f32 registers
    float lsum = 0.f;
    #pragma unroll
    for (int i = 0; i < 4; ++i) {
        int px = i * 4096 + t * 8;
        uint4 v = *(const uint4*)(pb + px);
        int y = px >> 7, xx = px & 127;
        *(uint4*)&img[y * 136 + xx] = v;
        uint4 av = *(const uint4*)(ab + px);
        unsigned int au[4] = {av.x, av.y, av.z, av.w};
        #pragma unroll
        for (int k = 0; k < 4; ++k) {
            float lo = softplus_fast(bf2f((unsigned short)(au[k] & 0xffff)) * scl + shf);
            float hi = softplus_fast(bf2f((unsigned short)(au[k] >> 16))    * scl + shf);
            lsum += lo + hi;
            aspf[i][2 * k]     = lo;
            aspf[i][2 * k + 1] = hi;
        }
    }
    lsum = block_reduce(lsum, sc);      // internal syncthreads covers img writes
    if (t == 0) s_inv = 1.f / lsum;
    __syncthreads();
    float inv = s_inv;
    w00 *= inv; w01 *= inv; w10 *= inv; w11 *= inv;
    int s = ix & 7;
    int ix8 = ix - s;
    int sh = (s & 3) * 16;
    bool s4 = s >= 4;
    #pragma unroll
    for (int i = 0; i < 4; ++i) {
        int px = i * 4096 + t * 8;
        int y = px >> 7, x0 = px & 127;
        int yy0 = y + iy, yy1 = yy0 + 1;
        float wA0 = (yy0 >= 0 && yy0 < 128) ? w00 : 0.f;
        float wA1 = (yy0 >= 0 && yy0 < 128) ? w01 : 0.f;
        float wB0 = (yy1 >= 0 && yy1 < 128) ? w10 : 0.f;
        float wB1 = (yy1 >= 0 && yy1 < 128) ? w11 : 0.f;
        int yc0 = min(max(yy0, 0), 127), yc1 = min(max(yy1, 0), 127);
        int w0 = x0 + ix8;
        uint4 z = {0u, 0u, 0u, 0u};
        uint4 qa0 = (w0 >= 0 && w0 <= 120)         ? *(const uint4*)&img[yc0 * 136 + w0]     : z;
        uint4 qa1 = (w0 + 8 >= 0 && w0 + 8 <= 120) ? *(const uint4*)&img[yc0 * 136 + w0 + 8] : z;
        uint4 qb0 = (w0 >= 0 && w0 <= 120)         ? *(const uint4*)&img[yc1 * 136 + w0]     : z;
        uint4 qb1 = (w0 + 8 >= 0 && w0 + 8 <= 120) ? *(const uint4*)&img[yc1 * 136 + w0 + 8] : z;
        Win9 va = extract9(qa0, qa1, s4, sh);
        Win9 vb = extract9(qb0, qb1, s4, sh);
        float m0 = (wA0*va.v0 + wA1*va.v1 + wB0*vb.v0 + wB1*vb.v1) * aspf[i][0];
        float m1 = (wA0*va.v1 + wA1*va.v2 + wB0*vb.v1 + wB1*vb.v2) * aspf[i][1];
        float m2 = (wA0*va.v2 + wA1*va.v3 + wB0*vb.v2 + wB1*vb.v3) * aspf[i][2];
        float m3 = (wA0*va.v3 + wA1*va.v4 + wB0*vb.v3 + wB1*vb.v4) * aspf[i][3];
        float m4 = (wA0*va.v4 + wA1*va.v5 + wB0*vb.v4 + wB1*vb.v5) * aspf[i][4];
        float m5 = (wA0*va.v5 + wA1*va.v6 + wB0*vb.v5 + wB1*vb.v6) * aspf[i][5];
        float m6 = (wA0*va.v6 + wA1*va.v7 + wB0*vb.v6 + wB1*vb.v7) * aspf[i][6];
        float m7 = (wA0*va.v7 + wA1*va.v8 + wB0*vb.v7 + wB1*vb.v8) * aspf[i][7];
        uint4 o;
        o.x = (unsigned int)f2bf(m0) | ((unsigned int)f2bf(m1) << 16);
        o.y = (unsigned int)f2bf(m2) | ((unsigned int)f2bf(m3) << 16);
        o.z = (unsigned int)f2bf(m4) | ((unsigned int)f2bf(m5) << 16);
        o.w = (unsigned int)f2bf(m6) | ((unsigned int)f2bf(m7) << 16);
        *(uint4*)(pb + px) = o;
    }
}

// ---------------- MFMA conv 128->64 + bias + skip -> skipS ----------------
__global__ __launch_bounds__(256) void conv_post_mfma(
        const unsigned short* __restrict__ m, const float* __restrict__ post_w,
        const float* __restrict__ post_b, const float* __restrict__ x,
        unsigned short* __restrict__ skipS) {
    __shared__ unsigned short mT[128 * 128];  // byte = px*256 + ((c*2) ^ ((px&7)<<4))
    int t = threadIdx.x;
    int P0 = blockIdx.x * 128;
    int b = P0 >> 14, poff = P0 & 16383;
    int cl = t & 31, q = t >> 5;
    #pragma unroll
    for (int pass = 0; pass < 4; ++pass) {
        int c = cl + pass * 32;
        const unsigned short* mrow = m + ((size_t)b * CD + c) * HWSZ + poff;
        #pragma unroll
        for (int h = 0; h < 2; ++h) {
            int px0 = h * 64 + q * 8;
            uint4 v = *(const uint4*)(mrow + px0);
            unsigned int u[4] = {v.x, v.y, v.z, v.w};
            #pragma unroll
            for (int j = 0; j < 8; ++j) {
                unsigned short val = (unsigned short)((u[j >> 1] >> ((j & 1) * 16)) & 0xffff);
                int byteoff = (px0 + j) * 256 + ((c * 2) ^ (j << 4));
                *(unsigned short*)((char*)mT + byteoff) = val;
            }
        }
    }
    __syncthreads();
    int ln = t & 63, wv = t >> 6;
    int o0 = (wv >> 1) * 32;
    int ph = (wv & 1) * 64;
    short8x aw[2][4];
    #pragma unroll
    for (int oi = 0; oi < 2; ++oi)
        #pragma unroll
        for (int kk = 0; kk < 4; ++kk) {
            int o = o0 + oi * 16 + (ln & 15);
            aw[oi][kk] = cvt_w8(post_w + o * 128 + kk * 32 + (ln >> 4) * 8);
        }
    floatx4 acc[2][4];
    #pragma unroll
    for (int oi = 0; oi < 2; ++oi)
        #pragma unroll
        for (int pi = 0; pi < 4; ++pi) acc[oi][pi] = floatx4{0.f, 0.f, 0.f, 0.f};
    #pragma unroll
    for (int kk = 0; kk < 4; ++kk)
        #pragma unroll
        for (int pi = 0; pi < 4; ++pi) {
            int px = ph + pi * 16 + (ln & 15);
            int cb = kk * 64 + (ln >> 4) * 16;
            short8x bf = *(const short8x*)((const char*)mT + px * 256 + (cb ^ ((px & 7) << 4)));
            #pragma unroll
            for (int oi = 0; oi < 2; ++oi)
                acc[oi][pi] = __builtin_amdgcn_mfma_f32_16x16x32_bf16(aw[oi][kk], bf, acc[oi][pi], 0, 0, 0);
        }
    #pragma unroll
    for (int oi = 0; oi < 2; ++oi) {
        float4 b4 = *(const float4*)(post_b + o0 + oi * 16 + (ln >> 4) * 4);
        float bb[4] = {b4.x, b4.y, b4.z, b4.w};
        #pragma unroll
        for (int pi = 0; pi < 4; ++pi) {
            int pxg = poff + ph + pi * 16 + (ln & 15);
            #pragma unroll
            for (int r = 0; r < 4; ++r) {
                int o = o0 + oi * 16 + (ln >> 4) * 4 + r;
                float val = acc[oi][pi][r] + bb[r] + x[((size_t)b * COUT + o) * HWSZ + pxg];
                skipS[((size_t)b * CD + o) * HWSZ + pxg] = f2bf(val);
            }
        }
    }
}

// ---------------- final BN + ReLU: skipS bf16 -> d_out fp32 ----------------
__global__ __launch_bounds__(256) void bn_relu_out(
        const unsigned short* __restrict__ skipS, float* __restrict__ out,
        const float* __restrict__ stats, const float* __restrict__ g,
        const float* __restrict__ bb) {
    const float N = 262144.f;
    int t = threadIdx.x;
    #pragma unroll
    for (int k = 0; k < 4; ++k) {
        size_t gidx = (size_t)blockIdx.x * 1024 + k * 256 + t;  // 8-elem index
        size_t e = gidx * 8;
        int b = (int)(e >> 20);
        int c = (int)(e >> 14) & 63;
        int px = (int)(e & 16383);
        float mean = stats[c * 2] / N;
        float rstd = rsqrtf(stats[c * 2 + 1] / N - mean * mean + BN_EPS);
        float gc = g[c], bbc = bb[c];
        uint4 v = *(const uint4*)(skipS + ((size_t)b * CD + c) * HWSZ + px);
        unsigned int u[4] = {v.x, v.y, v.z, v.w};
        float4 o0, o1;
        float* op[8] = {&o0.x, &o0.y, &o0.z, &o0.w, &o1.x, &o1.y, &o1.z, &o1.w};
        #pragma unroll
        for (int j = 0; j < 8; ++j) {
            float val = bf2f((unsigned short)((u[j >> 1] >> ((j & 1) * 16)) & 0xffff));
            *op[j] = fmaxf((val - mean) * rstd * gc + bbc, 0.f);
        }
        *(float4*)(out + e) = o0;
        *(float4*)(out + e + 4) = o1;
    }
}

extern "C" void kernel_launch(void* const* d_in, const int* in_sizes, int n_in,
                              void* d_out, int out_size, void* d_ws, size_t ws_size,
                              hipStream_t stream) {
    const float* x          = (const float*)d_in[0];
    const float* pre_w      = (const float*)d_in[1];
    const float* pre_b      = (const float*)d_in[2];
    const float* post_w     = (const float*)d_in[3];
    const float* post_b     = (const float*)d_in[4];
    const float* atten_w    = (const float*)d_in[5];
    const float* atten_b    = (const float*)d_in[6];
    const float* atten_bn_g = (const float*)d_in[7];
    const float* atten_bn_b = (const float*)d_in[8];
    const float* offsets    = (const float*)d_in[9];
    const float* bn_g       = (const float*)d_in[10];
    const float* bn_b       = (const float*)d_in[11];
    float* out = (float*)d_out;
    float* ws  = (float*)d_ws;

    if (ws_size < WS_TOTAL_BYTES) return;

    float* a_stats8 = ws + WS_ASTAT;
    float* o_stats  = ws + WS_OSTAT;
    unsigned short* big   = (unsigned short*)(ws + WS_BIG);  // out_pre -> m -> skipS
    unsigned short* a_buf = (unsigned short*)d_out;          // a_raw (bf16)

    hipMemsetAsync((void*)a_stats8, 0, (2048 + 128) * sizeof(float), stream);

    conv_pre_mfma<<<1024, 256, 0, stream>>>(x, pre_w, atten_w, pre_b, atten_b, big, a_buf, a_stats8);
    displace_bnsp_mul<<<2048, 512, 0, stream>>>(big, a_buf, a_stats8, atten_bn_g, atten_bn_b, offsets);
    conv_post_mfma<<<2048, 256, 0, stream>>>(big, post_w, post_b, x, big);
    chan_stats_bf16<<<dim3(64, 16), 256, 0, stream>>>(big, o_stats);
    bn_relu_out<<<2048, 256, 0, stream>>>(big, out, o_stats, bn_g, bn_b);
}

// Round 15
// 151.335 us; speedup vs baseline: 1.2264x; 1.0092x over previous
//
#include <hip/hip_runtime.h>

#define HWSZ   16384
#define CIN    64
#define CD     128
#define COUT   64
#define BN_EPS 1e-5f

typedef __attribute__((ext_vector_type(8))) short short8x;
typedef __attribute__((ext_vector_type(4))) float floatx4;

// ws layout (float offsets):
//  25344 : a_stats8[8][256]  (8 replicated slots, sum/sumsq per Cd channel)
//  27392 : o_stats8[8][128]  (8 replicated slots, sum/sumsq per Cout channel)
//  32768 : big region (64 MiB): out_pre (slots 0..127) -> m (in place) -> skipS (slots 0..63)
// d_out: a_raw (bf16) -> dead -> final fp32 output
#define WS_ASTAT 25344
#define WS_OSTAT 27392
#define WS_BIG   32768
#define WS_TOTAL_BYTES ((size_t)(32768 + 16777216) * 4)

__device__ __forceinline__ unsigned short f2bf(float f) {
    unsigned int u = __float_as_uint(f);
    u += 0x7fff + ((u >> 16) & 1);
    return (unsigned short)(u >> 16);
}
__device__ __forceinline__ float bf2f(unsigned short s) {
    return __uint_as_float(((unsigned int)s) << 16);
}
__device__ __forceinline__ float softplus_fast(float x) {
    return fmaxf(x, 0.f) + __logf(1.f + __expf(-fabsf(x)));
}
// works for 4 or 8 waves (sc must be float[8]); valid in thread 0
__device__ __forceinline__ float block_reduce(float v, float* sc) {
    #pragma unroll
    for (int off = 32; off >= 1; off >>= 1) v += __shfl_xor(v, off, 64);
    int wv = threadIdx.x >> 6, ln = threadIdx.x & 63;
    int nw = blockDim.x >> 6;
    if (ln == 0) sc[wv] = v;
    __syncthreads();
    float r = ((int)threadIdx.x < nw) ? sc[threadIdx.x] : 0.f;
    r += __shfl_xor(r, 1, 64);
    r += __shfl_xor(r, 2, 64);
    r += __shfl_xor(r, 4, 64);
    return r;
}

__device__ __forceinline__ short8x cvt_w8(const float* src) {
    float4 f0 = *(const float4*)(src);
    float4 f1 = *(const float4*)(src + 4);
    short8x w;
    w[0] = (short)f2bf(f0.x); w[1] = (short)f2bf(f0.y);
    w[2] = (short)f2bf(f0.z); w[3] = (short)f2bf(f0.w);
    w[4] = (short)f2bf(f1.x); w[5] = (short)f2bf(f1.y);
    w[6] = (short)f2bf(f1.z); w[7] = (short)f2bf(f1.w);
    return w;
}

// ---------------- conv_pre helpers ----------------
#define OBPAD 68   // row stride (ushorts)

__device__ __forceinline__ void pre_write_lds(unsigned short* wbuf, int c, int wv,
                                              const float4 ld[4]) {
    #pragma unroll
    for (int k = 0; k < 4; ++k) {
        int px = wv * 16 + k * 4;
        wbuf[(px + 0) * 72 + c] = f2bf(ld[k].x);
        wbuf[(px + 1) * 72 + c] = f2bf(ld[k].y);
        wbuf[(px + 2) * 72 + c] = f2bf(ld[k].z);
        wbuf[(px + 3) * 72 + c] = f2bf(ld[k].w);
    }
}

// swapped-operand compute: D[px][o]; results staged into ob[256][OBPAD]
__device__ __forceinline__ void pre_compute_tile(
        const unsigned short* buf, unsigned short* ob, int ln, int wv,
        const short8x wfrag[4][2], const float bv[4]) {
    floatx4 acc[4][4];
    #pragma unroll
    for (int oi = 0; oi < 4; ++oi)
        #pragma unroll
        for (int pi = 0; pi < 4; ++pi)
            acc[oi][pi] = floatx4{bv[oi], bv[oi], bv[oi], bv[oi]};
    #pragma unroll
    for (int kk = 0; kk < 2; ++kk)
        #pragma unroll
        for (int pi = 0; pi < 4; ++pi) {
            short8x xfrag = *(const short8x*)((const char*)buf +
                    (pi * 16 + (ln & 15)) * 144 + (kk * 32 + (ln >> 4) * 8) * 2);
            #pragma unroll
            for (int oi = 0; oi < 4; ++oi)
                acc[oi][pi] = __builtin_amdgcn_mfma_f32_16x16x32_bf16(
                        xfrag, wfrag[oi][kk], acc[oi][pi], 0, 0, 0);
        }
    #pragma unroll
    for (int oi = 0; oi < 4; ++oi) {
        int row = wv * 64 + oi * 16 + (ln & 15);
        #pragma unroll
        for (int pi = 0; pi < 4; ++pi) {
            int px = pi * 16 + (ln >> 4) * 4;
            ushort4 v;
            v.x = f2bf(acc[oi][pi][0]); v.y = f2bf(acc[oi][pi][1]);
            v.z = f2bf(acc[oi][pi][2]); v.w = f2bf(acc[oi][pi][3]);
            *(ushort4*)&ob[row * OBPAD + px] = v;
        }
    }
}

// ---------------- K1: MFMA conv1x1 (pre + atten) + fused a-stats ----------------
__global__ __launch_bounds__(256) void conv_pre_mfma(
        const float* __restrict__ x, const float* __restrict__ pre_w,
        const float* __restrict__ atten_w,
        const float* __restrict__ pre_b, const float* __restrict__ atten_b,
        unsigned short* __restrict__ out_pre, unsigned short* __restrict__ a_out,
        float* __restrict__ a_stats8) {
    __shared__ unsigned short xT[2][64 * 72];      // input staging (2 x 9 KB)
    __shared__ unsigned short ob[256 * OBPAD];     // output staging (34 KB)
    int t = threadIdx.x;
    int wv = t >> 6, ln = t & 63;
    int b = blockIdx.x >> 6;
    int poff = (blockIdx.x & 63) << 8;             // 256-px super-tile
    const float* xg = x + (size_t)b * CIN * HWSZ + poff;
    int c = ln;

    int o0 = wv * 64;
    short8x wfrag[4][2];
    #pragma unroll
    for (int oi = 0; oi < 4; ++oi)
        #pragma unroll
        for (int kk = 0; kk < 2; ++kk) {
            int row = o0 + oi * 16 + (ln & 15);
            int kcol = kk * 32 + (ln >> 4) * 8;
            const float* wsrc = (row < 128) ? (pre_w + row * 64)
                                            : (atten_w + (row - 128) * 64);
            wfrag[oi][kk] = cvt_w8(wsrc + kcol);
        }
    float bv[4];
    #pragma unroll
    for (int oi = 0; oi < 4; ++oi) {
        int og = o0 + oi * 16;
        bv[oi] = (og < 128) ? pre_b[og + (ln & 15)] : atten_b[og - 128 + (ln & 15)];
    }

    float asum[4] = {0.f, 0.f, 0.f, 0.f};
    float asq[4]  = {0.f, 0.f, 0.f, 0.f};

    float4 lda[4], ldb[4];
    #pragma unroll
    for (int k = 0; k < 4; ++k)
        lda[k] = *(const float4*)(xg + (size_t)c * HWSZ + 0 * 64 + wv * 16 + k * 4);
    pre_write_lds(xT[0], c, wv, lda);
    #pragma unroll
    for (int k = 0; k < 4; ++k)
        lda[k] = *(const float4*)(xg + (size_t)c * HWSZ + 1 * 64 + wv * 16 + k * 4);
    __syncthreads();

    #pragma unroll
    for (int tt = 0; tt < 4; ++tt) {
        if (tt == 0) {
            #pragma unroll
            for (int k = 0; k < 4; ++k)
                ldb[k] = *(const float4*)(xg + (size_t)c * HWSZ + 2 * 64 + wv * 16 + k * 4);
        } else if (tt == 1) {
            #pragma unroll
            for (int k = 0; k < 4; ++k)
                lda[k] = *(const float4*)(xg + (size_t)c * HWSZ + 3 * 64 + wv * 16 + k * 4);
        }
        pre_compute_tile(xT[tt & 1], ob, ln, wv, wfrag, bv);
        if (tt == 0)      pre_write_lds(xT[1], c, wv, lda);
        else if (tt == 1) pre_write_lds(xT[0], c, wv, ldb);
        else if (tt == 2) pre_write_lds(xT[1], c, wv, lda);
        __syncthreads();
        int ptile = poff + tt * 64;
        #pragma unroll
        for (int j = 0; j < 8; ++j) {
            int row = j * 32 + (t >> 3);
            int px  = (t & 7) * 8;
            uint4 v = *(const uint4*)&ob[row * OBPAD + px];
            unsigned short* dst = (row < 128) ? out_pre : a_out;
            int o = row & 127;
            *(uint4*)(dst + ((size_t)b * CD + o) * HWSZ + ptile + px) = v;
            if (j >= 4) {
                unsigned int u[4] = {v.x, v.y, v.z, v.w};
                float s = 0.f, q = 0.f;
                #pragma unroll
                for (int k = 0; k < 4; ++k) {
                    float lo = bf2f((unsigned short)(u[k] & 0xffff));
                    float hi = bf2f((unsigned short)(u[k] >> 16));
                    s += lo + hi;
                    q += lo * lo + hi * hi;
                }
                asum[j - 4] += s;
                asq[j - 4]  += q;
            }
        }
        __syncthreads();
    }
    float* slot = a_stats8 + (blockIdx.x & 7) * 256;
    #pragma unroll
    for (int jj = 0; jj < 4; ++jj) {
        float s = asum[jj], q = asq[jj];
        s += __shfl_xor(s, 1, 64); q += __shfl_xor(q, 1, 64);
        s += __shfl_xor(s, 2, 64); q += __shfl_xor(q, 2, 64);
        s += __shfl_xor(s, 4, 64); q += __shfl_xor(q, 4, 64);
        if ((t & 7) == 0) {
            int o = (jj + 4) * 32 + (t >> 3) - 128;
            atomicAdd(&slot[2 * o],     s);
            atomicAdd(&slot[2 * o + 1], q);
        }
    }
}

// ---------------- fused: BN+softplus (f32 regs) + spat-reduce + displace + mul ----------------
struct Win9 { float v0,v1,v2,v3,v4,v5,v6,v7,v8; };
__device__ __forceinline__ Win9 extract9(uint4 qa, uint4 qb, bool s4, int sh) {
    unsigned long long A0 = ((unsigned long long)qa.y << 32) | qa.x;
    unsigned long long A1 = ((unsigned long long)qa.w << 32) | qa.z;
    unsigned long long A2 = ((unsigned long long)qb.y << 32) | qb.x;
    unsigned long long A3 = ((unsigned long long)qb.w << 32) | qb.z;
    unsigned long long B0 = s4 ? A1 : A0;
    unsigned long long B1 = s4 ? A2 : A1;
    unsigned long long B2 = s4 ? A3 : A2;
    unsigned long long r0 = sh ? ((B0 >> sh) | (B1 << (64 - sh))) : B0;
    unsigned long long r1 = sh ? ((B1 >> sh) | (B2 << (64 - sh))) : B1;
    unsigned int v8w = (unsigned int)(sh ? (B2 >> sh) : B2);
    Win9 w;
    w.v0 = bf2f((unsigned short)(r0 >>  0)); w.v1 = bf2f((unsigned short)(r0 >> 16));
    w.v2 = bf2f((unsigned short)(r0 >> 32)); w.v3 = bf2f((unsigned short)(r0 >> 48));
    w.v4 = bf2f((unsigned short)(r1 >>  0)); w.v5 = bf2f((unsigned short)(r1 >> 16));
    w.v6 = bf2f((unsigned short)(r1 >> 32)); w.v7 = bf2f((unsigned short)(r1 >> 48));
    w.v8 = bf2f((unsigned short)(v8w & 0xffff));
    return w;
}

__global__ __launch_bounds__(512) void displace_bnsp_mul(
        unsigned short* __restrict__ pre, const unsigned short* __restrict__ a_raw,
        const float* __restrict__ stats8, const float* __restrict__ g,
        const float* __restrict__ bb, const float* __restrict__ offsets) {
    __shared__ unsigned short img[128 * 136];
    __shared__ float sc[8];
    __shared__ float s_inv;
    int bc = blockIdx.x;
    int cc = bc & 127;
    float dy = offsets[(cc >> 2) * 2 + 0];
    float dx = offsets[(cc >> 2) * 2 + 1];
    float fy = floorf(dy), fx = floorf(dx);
    float wy = dy - fy, wx = dx - fx;
    int iy = (int)fy, ix = (int)fx;
    float w00 = (1.f - wy) * (1.f - wx);
    float w01 = (1.f - wy) * wx;
    float w10 = wy * (1.f - wx);
    float w11 = wy * wx;
    float sum = 0.f, sq = 0.f;
    #pragma unroll
    for (int k = 0; k < 8; ++k) {
        sum += stats8[k * 256 + 2 * cc];
        sq  += stats8[k * 256 + 2 * cc + 1];
    }
    const float N = 262144.f;
    float mean = sum / N;
    float var  = sq / N - mean * mean;
    float rstd = rsqrtf(var + BN_EPS);
    float scl = rstd * g[cc];
    float shf = bb[cc] - mean * scl;
    unsigned short* pb = pre + (size_t)bc * HWSZ;
    const unsigned short* ab = a_raw + (size_t)bc * HWSZ;
    int t = threadIdx.x;
    float aspf[4][8];
    float lsum = 0.f;
    #pragma unroll
    for (int i = 0; i < 4; ++i) {
        int px = i * 4096 + t * 8;
        uint4 v = *(const uint4*)(pb + px);
        int y = px >> 7, xx = px & 127;
        *(uint4*)&img[y * 136 + xx] = v;
        uint4 av = *(const uint4*)(ab + px);
        unsigned int au[4] = {av.x, av.y, av.z, av.w};
        #pragma unroll
        for (int k = 0; k < 4; ++k) {
            float lo = softplus_fast(bf2f((unsigned short)(au[k] & 0xffff)) * scl + shf);
            float hi = softplus_fast(bf2f((unsigned short)(au[k] >> 16))    * scl + shf);
            lsum += lo + hi;
            aspf[i][2 * k]     = lo;
            aspf[i][2 * k + 1] = hi;
        }
    }
    lsum = block_reduce(lsum, sc);
    if (t == 0) s_inv = 1.f / lsum;
    __syncthreads();
    float inv = s_inv;
    w00 *= inv; w01 *= inv; w10 *= inv; w11 *= inv;
    int s = ix & 7;
    int ix8 = ix - s;
    int sh = (s & 3) * 16;
    bool s4 = s >= 4;
    #pragma unroll
    for (int i = 0; i < 4; ++i) {
        int px = i * 4096 + t * 8;
        int y = px >> 7, x0 = px & 127;
        int yy0 = y + iy, yy1 = yy0 + 1;
        float wA0 = (yy0 >= 0 && yy0 < 128) ? w00 : 0.f;
        float wA1 = (yy0 >= 0 && yy0 < 128) ? w01 : 0.f;
        float wB0 = (yy1 >= 0 && yy1 < 128) ? w10 : 0.f;
        float wB1 = (yy1 >= 0 && yy1 < 128) ? w11 : 0.f;
        int yc0 = min(max(yy0, 0), 127), yc1 = min(max(yy1, 0), 127);
        int w0 = x0 + ix8;
        uint4 z = {0u, 0u, 0u, 0u};
        uint4 qa0 = (w0 >= 0 && w0 <= 120)         ? *(const uint4*)&img[yc0 * 136 + w0]     : z;
        uint4 qa1 = (w0 + 8 >= 0 && w0 + 8 <= 120) ? *(const uint4*)&img[yc0 * 136 + w0 + 8] : z;
        uint4 qb0 = (w0 >= 0 && w0 <= 120)         ? *(const uint4*)&img[yc1 * 136 + w0]     : z;
        uint4 qb1 = (w0 + 8 >= 0 && w0 + 8 <= 120) ? *(const uint4*)&img[yc1 * 136 + w0 + 8] : z;
        Win9 va = extract9(qa0, qa1, s4, sh);
        Win9 vb = extract9(qb0, qb1, s4, sh);
        float m0 = (wA0*va.v0 + wA1*va.v1 + wB0*vb.v0 + wB1*vb.v1) * aspf[i][0];
        float m1 = (wA0*va.v1 + wA1*va.v2 + wB0*vb.v1 + wB1*vb.v2) * aspf[i][1];
        float m2 = (wA0*va.v2 + wA1*va.v3 + wB0*vb.v2 + wB1*vb.v3) * aspf[i][2];
        float m3 = (wA0*va.v3 + wA1*va.v4 + wB0*vb.v3 + wB1*vb.v4) * aspf[i][3];
        float m4 = (wA0*va.v4 + wA1*va.v5 + wB0*vb.v4 + wB1*vb.v5) * aspf[i][4];
        float m5 = (wA0*va.v5 + wA1*va.v6 + wB0*vb.v5 + wB1*vb.v6) * aspf[i][5];
        float m6 = (wA0*va.v6 + wA1*va.v7 + wB0*vb.v6 + wB1*vb.v7) * aspf[i][6];
        float m7 = (wA0*va.v7 + wA1*va.v8 + wB0*vb.v7 + wB1*vb.v8) * aspf[i][7];
        uint4 o;
        o.x = (unsigned int)f2bf(m0) | ((unsigned int)f2bf(m1) << 16);
        o.y = (unsigned int)f2bf(m2) | ((unsigned int)f2bf(m3) << 16);
        o.z = (unsigned int)f2bf(m4) | ((unsigned int)f2bf(m5) << 16);
        o.w = (unsigned int)f2bf(m6) | ((unsigned int)f2bf(m7) << 16);
        *(uint4*)(pb + px) = o;
    }
}

// ---------------- MFMA conv 128->64 + bias + skip (D=[px][o], coalesced) + fused o-stats ----------------
#define OPPAD 132   // skip-tile row stride (ushorts)
__global__ __launch_bounds__(256) void conv_post_mfma(
        const unsigned short* __restrict__ m, const float* __restrict__ post_w,
        const float* __restrict__ post_b, const float* __restrict__ x,
        unsigned short* __restrict__ skipS, float* __restrict__ o_stats8) {
    __shared__ unsigned short mT[128 * 128];   // 32 KB, byte = px*256 + ((c*2) ^ ((px&7)<<4))
    __shared__ unsigned short ot[64 * OPPAD];  // 16.9 KB output staging
    int t = threadIdx.x;
    int P0 = blockIdx.x * 128;
    int b = P0 >> 14, poff = P0 & 16383;
    int cl = t & 31, q = t >> 5;
    #pragma unroll
    for (int pass = 0; pass < 4; ++pass) {
        int c = cl + pass * 32;
        const unsigned short* mrow = m + ((size_t)b * CD + c) * HWSZ + poff;
        #pragma unroll
        for (int h = 0; h < 2; ++h) {
            int px0 = h * 64 + q * 8;
            uint4 v = *(const uint4*)(mrow + px0);
            unsigned int u[4] = {v.x, v.y, v.z, v.w};
            #pragma unroll
            for (int j = 0; j < 8; ++j) {
                unsigned short val = (unsigned short)((u[j >> 1] >> ((j & 1) * 16)) & 0xffff);
                int byteoff = (px0 + j) * 256 + ((c * 2) ^ (j << 4));
                *(unsigned short*)((char*)mT + byteoff) = val;
            }
        }
    }
    __syncthreads();
    int ln = t & 63, wv = t >> 6;
    int o0 = (wv >> 1) * 32;
    int ph = (wv & 1) * 64;
    short8x aw[2][4];
    #pragma unroll
    for (int oi = 0; oi < 2; ++oi)
        #pragma unroll
        for (int kk = 0; kk < 4; ++kk) {
            int o = o0 + oi * 16 + (ln & 15);
            aw[oi][kk] = cvt_w8(post_w + o * 128 + kk * 32 + (ln >> 4) * 8);
        }
    floatx4 acc[2][4];
    #pragma unroll
    for (int oi = 0; oi < 2; ++oi)
        #pragma unroll
        for (int pi = 0; pi < 4; ++pi) acc[oi][pi] = floatx4{0.f, 0.f, 0.f, 0.f};
    #pragma unroll
    for (int kk = 0; kk < 4; ++kk)
        #pragma unroll
        for (int pi = 0; pi < 4; ++pi) {
            int px = ph + pi * 16 + (ln & 15);
            int cb = kk * 64 + (ln >> 4) * 16;
            short8x mf = *(const short8x*)((const char*)mT + px * 256 + (cb ^ ((px & 7) << 4)));
            #pragma unroll
            for (int oi = 0; oi < 2; ++oi)
                acc[oi][pi] = __builtin_amdgcn_mfma_f32_16x16x32_bf16(mf, aw[oi][kk], acc[oi][pi], 0, 0, 0);
        }
    // epilogue: D[px][o] -> + bias + x skip (float4) -> stage ushort4 to ot
    #pragma unroll
    for (int oi = 0; oi < 2; ++oi) {
        int o = o0 + oi * 16 + (ln & 15);
        float bvp = post_b[o];
        #pragma unroll
        for (int pi = 0; pi < 4; ++pi) {
            int pxl = ph + pi * 16 + (ln >> 4) * 4;
            float4 xv = *(const float4*)(x + ((size_t)b * COUT + o) * HWSZ + poff + pxl);
            ushort4 sv;
            sv.x = f2bf(acc[oi][pi][0] + bvp + xv.x);
            sv.y = f2bf(acc[oi][pi][1] + bvp + xv.y);
            sv.z = f2bf(acc[oi][pi][2] + bvp + xv.z);
            sv.w = f2bf(acc[oi][pi][3] + bvp + xv.w);
            *(ushort4*)&ot[o * OPPAD + pxl] = sv;
        }
    }
    __syncthreads();
    // store phase: coalesced dwordx4 + fused o-stats
    float osum[4] = {0.f, 0.f, 0.f, 0.f};
    float osq[4]  = {0.f, 0.f, 0.f, 0.f};
    #pragma unroll
    for (int j = 0; j < 4; ++j) {
        int o  = j * 16 + (t >> 4);
        int px = (t & 15) * 8;
        uint4 v = *(const uint4*)&ot[o * OPPAD + px];
        *(uint4*)(skipS + ((size_t)b * CD + o) * HWSZ + poff + px) = v;
        unsigned int u[4] = {v.x, v.y, v.z, v.w};
        float s = 0.f, q = 0.f;
        #pragma unroll
        for (int k = 0; k < 4; ++k) {
            float lo = bf2f((unsigned short)(u[k] & 0xffff));
            float hi = bf2f((unsigned short)(u[k] >> 16));
            s += lo + hi;
            q += lo * lo + hi * hi;
        }
        osum[j] += s;
        osq[j]  += q;
    }
    float* slot = o_stats8 + (blockIdx.x & 7) * 128;
    #pragma unroll
    for (int j = 0; j < 4; ++j) {
        float s = osum[j], q = osq[j];
        s += __shfl_xor(s, 1, 64); q += __shfl_xor(q, 1, 64);
        s += __shfl_xor(s, 2, 64); q += __shfl_xor(q, 2, 64);
        s += __shfl_xor(s, 4, 64); q += __shfl_xor(q, 4, 64);
        s += __shfl_xor(s, 8, 64); q += __shfl_xor(q, 8, 64);
        if ((t & 15) == 0) {
            int o = j * 16 + (t >> 4);
            atomicAdd(&slot[2 * o],     s);
            atomicAdd(&slot[2 * o + 1], q);
        }
    }
}

// ---------------- final BN + ReLU: skipS bf16 -> d_out fp32 ----------------
__global__ __launch_bounds__(256) void bn_relu_out(
        const unsigned short* __restrict__ skipS, float* __restrict__ out,
        const float* __restrict__ stats8, const float* __restrict__ g,
        const float* __restrict__ bb) {
    const float N = 262144.f;
    int t = threadIdx.x;
    #pragma unroll
    for (int k = 0; k < 4; ++k) {
        size_t gidx = (size_t)blockIdx.x * 1024 + k * 256 + t;  // 8-elem index
        size_t e = gidx * 8;
        int b = (int)(e >> 20);
        int c = (int)(e >> 14) & 63;
        int px = (int)(e & 16383);
        float sum = 0.f, sq = 0.f;
        #pragma unroll
        for (int kk = 0; kk < 8; ++kk) {
            sum += stats8[kk * 128 + 2 * c];
            sq  += stats8[kk * 128 + 2 * c + 1];
        }
        float mean = sum / N;
        float rstd = rsqrtf(sq / N - mean * mean + BN_EPS);
        float gc = g[c], bbc = bb[c];
        uint4 v = *(const uint4*)(skipS + ((size_t)b * CD + c) * HWSZ + px);
        unsigned int u[4] = {v.x, v.y, v.z, v.w};
        float4 o0, o1;
        float* op[8] = {&o0.x, &o0.y, &o0.z, &o0.w, &o1.x, &o1.y, &o1.z, &o1.w};
        #pragma unroll
        for (int j = 0; j < 8; ++j) {
            float val = bf2f((unsigned short)((u[j >> 1] >> ((j & 1) * 16)) & 0xffff));
            *op[j] = fmaxf((val - mean) * rstd * gc + bbc, 0.f);
        }
        *(float4*)(out + e) = o0;
        *(float4*)(out + e + 4) = o1;
    }
}

extern "C" void kernel_launch(void* const* d_in, const int* in_sizes, int n_in,
                              void* d_out, int out_size, void* d_ws, size_t ws_size,
                              hipStream_t stream) {
    const float* x          = (const float*)d_in[0];
    const float* pre_w      = (const float*)d_in[1];
    const float* pre_b      = (const float*)d_in[2];
    const float* post_w     = (const float*)d_in[3];
    const float* post_b     = (const float*)d_in[4];
    const float* atten_w    = (const float*)d_in[5];
    const float* atten_b    = (const float*)d_in[6];
    const float* atten_bn_g = (const float*)d_in[7];
    const float* atten_bn_b = (const float*)d_in[8];
    const float* offsets    = (const float*)d_in[9];
    const float* bn_g       = (const float*)d_in[10];
    const float* bn_b       = (const float*)d_in[11];
    float* out = (float*)d_out;
    float* ws  = (float*)d_ws;

    if (ws_size < WS_TOTAL_BYTES) return;

    float* a_stats8 = ws + WS_ASTAT;
    float* o_stats8 = ws + WS_OSTAT;
    unsigned short* big   = (unsigned short*)(ws + WS_BIG);  // out_pre -> m -> skipS
    unsigned short* a_buf = (unsigned short*)d_out;          // a_raw (bf16)

    hipMemsetAsync((void*)a_stats8, 0, (2048 + 1024) * sizeof(float), stream);

    conv_pre_mfma<<<1024, 256, 0, stream>>>(x, pre_w, atten_w, pre_b, atten_b, big, a_buf, a_stats8);
    displace_bnsp_mul<<<2048, 512, 0, stream>>>(big, a_buf, a_stats8, atten_bn_g, atten_bn_b, offsets);
    conv_post_mfma<<<2048, 256, 0, stream>>>(big, post_w, post_b, x, big, o_stats8);
    bn_relu_out<<<2048, 256, 0, stream>>>(big, out, o_stats8, bn_g, bn_b);
}